// Round 2
// baseline (458.892 us; speedup 1.0000x reference)
//
#include <hip/hip_runtime.h>
#include <math.h>

#define TRI(i,j) (((i)*((i)+1))/2 + (j))

__device__ __forceinline__ float tanh_fast(float v) {
  v = fminf(fmaxf(v, -15.0f), 15.0f);
  float t = __expf(2.0f * v);                       // e^{2v}
  return fmaf(-2.0f, __builtin_amdgcn_rcpf(t + 1.0f), 1.0f);
}

__device__ __forceinline__ float rsum16(float v) {
  v += __shfl_xor(v, 1, 64);
  v += __shfl_xor(v, 2, 64);
  v += __shfl_xor(v, 4, 64);
  v += __shfl_xor(v, 8, 64);
  return v;
}

// Pack per-hidden-unit records: [W1[0..7][j], b1[j], W2[j][0..5], pad] = 16 floats (64B)
__global__ void pack_weights(const float* __restrict__ W1,
                             const float* __restrict__ b1,
                             const float* __restrict__ W2,
                             float* __restrict__ wpk) {
  int j = threadIdx.x;   // 0..63
  float* r = wpk + (j << 4);
#pragma unroll
  for (int k = 0; k < 8; ++k) r[k] = W1[k * 64 + j];
  r[8] = b1[j];
#pragma unroll
  for (int i = 0; i < 6; ++i) r[9 + i] = W2[j * 6 + i];
  r[15] = 0.0f;
}

// 16 lanes per batch: lane r handles sigma point r (r=0..12 active; 13..15 are
// zero-weight clones of sigma 0). j-loop stays wave-uniform -> scalar weight loads.
__launch_bounds__(256, 4)
__global__ void ukf_kernel(const float* __restrict__ gx,
                           const float* __restrict__ gP,
                           const float* __restrict__ gu,
                           const float* __restrict__ gy,
                           const float* __restrict__ gLQ,
                           const float* __restrict__ gLR,
                           const float* __restrict__ gb2,
                           const float* __restrict__ wpk,
                           float* __restrict__ out, int B) {
  int t = blockIdx.x * blockDim.x + threadIdx.x;
  int b = t >> 4;
  int r = t & 15;
  if (b >= B) return;

  // ---- per-batch inputs (same addr across the 16 group lanes -> L1 broadcast) ----
  float x0[6];
  {
    const float* xb = gx + b * 6;
    float2 t0 = *(const float2*)(xb);
    float2 t1 = *(const float2*)(xb + 2);
    float2 t2 = *(const float2*)(xb + 4);
    x0[0]=t0.x; x0[1]=t0.y; x0[2]=t1.x; x0[3]=t1.y; x0[4]=t2.x; x0[5]=t2.y;
  }
  float2 uu = *(const float2*)(gu + b * 2);
  float yy0, yy1, yy2;
  { const float* yb = gy + b * 3; yy0 = yb[0]; yy1 = yb[1]; yy2 = yb[2]; }

  // ---- base = 0.75*(P+P^T) + 1e-5 I ; cholesky -> Lt (lower tri, per-lane dup) ----
  float Lt[21];
  {
    float Pf[36];
    const float4* p4 = (const float4*)(gP + b * 36);
#pragma unroll
    for (int q = 0; q < 9; ++q) {
      float4 v = p4[q];
      Pf[q*4+0]=v.x; Pf[q*4+1]=v.y; Pf[q*4+2]=v.z; Pf[q*4+3]=v.w;
    }
    float base[21];
#pragma unroll
    for (int i = 0; i < 6; ++i)
#pragma unroll
      for (int j = 0; j <= i; ++j)
        base[TRI(i,j)] = 0.75f * (Pf[i*6+j] + Pf[j*6+i]) + ((i==j) ? 1e-5f : 0.0f);
#pragma unroll
    for (int k = 0; k < 6; ++k) {
      float s = base[TRI(k,k)];
#pragma unroll
      for (int m2 = 0; m2 < k; ++m2) s = fmaf(-Lt[TRI(k,m2)], Lt[TRI(k,m2)], s);
      float d = sqrtf(s);
      Lt[TRI(k,k)] = d;
      float inv = 1.0f / d;
#pragma unroll
      for (int i = k + 1; i < 6; ++i) {
        float s2 = base[TRI(i,k)];
#pragma unroll
        for (int m2 = 0; m2 < k; ++m2) s2 = fmaf(-Lt[TRI(i,m2)], Lt[TRI(k,m2)], s2);
        Lt[TRI(i,k)] = s2 * inv;
      }
    }
  }

  // ---- per-lane sigma point: column select (no LDS, v_cndmask) ----
  bool  valid = (r <= 12);
  int   c   = (r == 0) ? 0 : ((r <= 6) ? (r - 1) : (r - 7));
  float sgn = (!valid || r == 0) ? 0.0f : ((r <= 6) ? 1.0f : -1.0f);
  float wm  = (r == 0) ? -3.0f   : (valid ? (1.0f/3.0f) : 0.0f);
  float wc  = (r == 0) ? -0.25f  : (valid ? (1.0f/3.0f) : 0.0f);

  float xs[6];
#pragma unroll
  for (int i = 0; i < 6; ++i) {
    float v = 0.0f;
#pragma unroll
    for (int k = 0; k <= i; ++k) v = (c == k) ? Lt[TRI(i,k)] : v;
    xs[i] = fmaf(sgn, v, x0[i]);
  }

  // ---- uniform small constants: Q, R, b2 (wave-uniform scalar loads) ----
  float Qm[21];
#pragma unroll
  for (int i = 0; i < 6; ++i)
#pragma unroll
    for (int j = 0; j <= i; ++j) {
      float s = (i==j) ? 1e-7f : 0.0f;
#pragma unroll
      for (int k = 0; k <= j; ++k) s = fmaf(gLQ[i*6+k], gLQ[j*6+k], s);
      Qm[TRI(i,j)] = s;
    }
  float Rm[6];
#pragma unroll
  for (int i = 0; i < 3; ++i)
#pragma unroll
    for (int j = 0; j <= i; ++j) {
      float s = (i==j) ? 1e-7f : 0.0f;
#pragma unroll
      for (int k = 0; k <= j; ++k) s = fmaf(gLR[i*3+k], gLR[j*3+k], s);
      Rm[TRI(i,j)] = s;
    }

  // ---- RK4 on this lane's sigma point ----
  float xin[8];
  xin[6] = uu.x; xin[7] = uu.y;
  float ksum[6]  = {0,0,0,0,0,0};
  float kprev[6] = {0,0,0,0,0,0};
#pragma unroll 1
  for (int st = 0; st < 4; ++st) {
    float cin = (st == 3) ? 0.01f : 0.005f;   // dt, dt/2 (st==0 nulled by kprev=0)
#pragma unroll
    for (int i = 0; i < 6; ++i) xin[i] = fmaf(cin, kprev[i], xs[i]);
    float acc0 = gb2[0], acc1 = gb2[1], acc2 = gb2[2],
          acc3 = gb2[3], acc4 = gb2[4], acc5 = gb2[5];
#pragma unroll 4
    for (int j = 0; j < 64; ++j) {
      const float* wr = wpk + (j << 4);       // uniform addr -> s_load_dwordx16
      float m0 = fmaf(xin[0], wr[0], xin[1] * wr[1]);
      float m1 = fmaf(xin[2], wr[2], xin[3] * wr[3]);
      float m2 = fmaf(xin[4], wr[4], xin[5] * wr[5]);
      float m3 = fmaf(xin[6], wr[6], fmaf(xin[7], wr[7], wr[8]));
      float h  = tanh_fast((m0 + m1) + (m2 + m3));
      acc0 = fmaf(h, wr[9],  acc0);
      acc1 = fmaf(h, wr[10], acc1);
      acc2 = fmaf(h, wr[11], acc2);
      acc3 = fmaf(h, wr[12], acc3);
      acc4 = fmaf(h, wr[13], acc4);
      acc5 = fmaf(h, wr[14], acc5);
    }
    float wks = (st == 0 || st == 3) ? 1.0f : 2.0f;
    kprev[0]=acc0; kprev[1]=acc1; kprev[2]=acc2; kprev[3]=acc3; kprev[4]=acc4; kprev[5]=acc5;
#pragma unroll
    for (int i = 0; i < 6; ++i) ksum[i] = fmaf(wks, kprev[i], ksum[i]);
  }

  // ---- this lane's delta, then group reduction of moments ----
  float dl[6];
#pragma unroll
  for (int i = 0; i < 6; ++i) {
    float sp = fmaf(0.01f/6.0f, ksum[i], xs[i]);   // sigma_pred
    dl[i] = sp - x0[i];
  }

  float cb[6], db[6];
#pragma unroll
  for (int i = 0; i < 6; ++i) {
    float d0 = __shfl(dl[i], 0, 16);               // lane-0 (sigma 0) delta
    cb[i] = rsum16(wc * dl[i]);                    // sum Wc * delta
    db[i] = cb[i] - 2.75f * d0;                    // wm0-wc0 = -2.75 correction
  }
  float U[21];
#pragma unroll
  for (int i = 0; i < 6; ++i) {
    float wd = wc * dl[i];
#pragma unroll
    for (int j = 0; j <= i; ++j) U[TRI(i,j)] = rsum16(wd * dl[j]);
  }

  // ---- moments -> D = sum Wc dx dx^T (all lanes redundant from here) ----
  float xp[6];
#pragma unroll
  for (int i = 0; i < 6; ++i) xp[i] = x0[i] + db[i];
  float D[21];
#pragma unroll
  for (int i = 0; i < 6; ++i)
#pragma unroll
    for (int j = 0; j <= i; ++j) {
      float v = U[TRI(i,j)];
      v -= cb[i] * db[j];
      v -= db[i] * cb[j];
      v = fmaf(3.75f * db[i], db[j], v);   // sum(Wc) = 3.75
      D[TRI(i,j)] = v;
    }

  // ---- S = D[:3,:3] + R ; inverse of S+1e-5 I via adjugate ----
  float s00 = D[TRI(0,0)] + Rm[TRI(0,0)];
  float s10 = D[TRI(1,0)] + Rm[TRI(1,0)];
  float s11 = D[TRI(1,1)] + Rm[TRI(1,1)];
  float s20 = D[TRI(2,0)] + Rm[TRI(2,0)];
  float s21 = D[TRI(2,1)] + Rm[TRI(2,1)];
  float s22 = D[TRI(2,2)] + Rm[TRI(2,2)];
  float a00 = s00 + 1e-5f, a11 = s11 + 1e-5f, a22 = s22 + 1e-5f;
  float a10 = s10, a20 = s20, a21 = s21;
  float adj00 = a11*a22 - a21*a21;
  float adj01 = a20*a21 - a10*a22;
  float adj02 = a10*a21 - a11*a20;
  float adj11 = a00*a22 - a20*a20;
  float adj12 = a10*a20 - a00*a21;
  float adj22 = a00*a11 - a10*a10;
  float det  = a00*adj00 + a10*adj01 + a20*adj02;
  float idet = 1.0f / det;
  float I00 = adj00*idet, I01 = adj01*idet, I02 = adj02*idet;
  float I11 = adj11*idet, I12 = adj12*idet, I22 = adj22*idet;

#define DS(i,j) ((i) >= (j) ? D[TRI(i,j)] : D[TRI(j,i)])
  float K_[18];
#pragma unroll
  for (int i = 0; i < 6; ++i) {
    float c0 = DS(i,0), c1 = DS(i,1), c2 = DS(i,2);   // cross = D[:, :3]
    K_[i*3+0] = c0*I00 + c1*I01 + c2*I02;
    K_[i*3+1] = c0*I01 + c1*I11 + c2*I12;
    K_[i*3+2] = c0*I02 + c1*I12 + c2*I22;
  }
  float inn0 = yy0 - xp[0], inn1 = yy1 - xp[1], inn2 = yy2 - xp[2];
  float xu[6];
#pragma unroll
  for (int i = 0; i < 6; ++i)
    xu[i] = xp[i] + K_[i*3]*inn0 + K_[i*3+1]*inn1 + K_[i*3+2]*inn2;

  float KS[18];
#pragma unroll
  for (int i = 0; i < 6; ++i) {
    float k0 = K_[i*3], k1 = K_[i*3+1], k2 = K_[i*3+2];
    KS[i*3+0] = k0*s00 + k1*s10 + k2*s20;
    KS[i*3+1] = k0*s10 + k1*s11 + k2*s21;
    KS[i*3+2] = k0*s20 + k1*s21 + k2*s22;
  }
  float Pu[21];
#pragma unroll
  for (int i = 0; i < 6; ++i)
#pragma unroll
    for (int j = 0; j <= i; ++j) {
      float v = D[TRI(i,j)] + Qm[TRI(i,j)];   // P_pred
      v -= KS[i*3]*K_[j*3] + KS[i*3+1]*K_[j*3+1] + KS[i*3+2]*K_[j*3+2];
      Pu[TRI(i,j)] = v + ((i==j) ? 1e-4f : 0.0f);
    }

  // ---- stores: group leader only ----
  if (r == 0) {
    float* o_xu = out;
    float* o_Pu = out + (size_t)6  * B;
    float* o_xp = out + (size_t)42 * B;
    float* o_Pp = out + (size_t)48 * B;
    float* o_yp = out + (size_t)84 * B;
    float* o_S  = out + (size_t)87 * B;
    float* o_K  = out + (size_t)96 * B;

    {
      float* p = o_xu + b * 6;
      ((float2*)p)[0] = make_float2(xu[0], xu[1]);
      ((float2*)p)[1] = make_float2(xu[2], xu[3]);
      ((float2*)p)[2] = make_float2(xu[4], xu[5]);
    }
    {
      float* p = o_Pu + b * 36;
#pragma unroll
      for (int i = 0; i < 6; ++i)
#pragma unroll
        for (int j = 0; j < 6; j += 2) {
          float v0 = (i>=j)   ? Pu[TRI(i,j)]   : Pu[TRI(j,i)];
          float v1 = (i>=j+1) ? Pu[TRI(i,j+1)] : Pu[TRI(j+1,i)];
          *(float2*)(p + i*6 + j) = make_float2(v0, v1);
        }
    }
    {
      float* p = o_xp + b * 6;
      ((float2*)p)[0] = make_float2(xp[0], xp[1]);
      ((float2*)p)[1] = make_float2(xp[2], xp[3]);
      ((float2*)p)[2] = make_float2(xp[4], xp[5]);
    }
    {
      float* p = o_Pp + b * 36;
#pragma unroll
      for (int i = 0; i < 6; ++i)
#pragma unroll
        for (int j = 0; j < 6; j += 2) {
          float v0 = ((i>=j)   ? D[TRI(i,j)]   : D[TRI(j,i)])   + ((i>=j)   ? Qm[TRI(i,j)]   : Qm[TRI(j,i)]);
          float v1 = ((i>=j+1) ? D[TRI(i,j+1)] : D[TRI(j+1,i)]) + ((i>=j+1) ? Qm[TRI(i,j+1)] : Qm[TRI(j+1,i)]);
          *(float2*)(p + i*6 + j) = make_float2(v0, v1);
        }
    }
    {
      float* p = o_yp + b * 3;
      p[0] = xp[0]; p[1] = xp[1]; p[2] = xp[2];
    }
    {
      float* p = o_S + b * 9;
      p[0]=s00; p[1]=s10; p[2]=s20;
      p[3]=s10; p[4]=s11; p[5]=s21;
      p[6]=s20; p[7]=s21; p[8]=s22;
    }
    {
      float* p = o_K + b * 18;
#pragma unroll
      for (int i = 0; i < 9; ++i)
        ((float2*)p)[i] = make_float2(K_[i*2], K_[i*2+1]);
    }
  }
}

extern "C" void kernel_launch(void* const* d_in, const int* in_sizes, int n_in,
                              void* d_out, int out_size, void* d_ws, size_t ws_size,
                              hipStream_t stream) {
  const float* x  = (const float*)d_in[0];
  const float* P  = (const float*)d_in[1];
  const float* u  = (const float*)d_in[2];
  const float* y  = (const float*)d_in[3];
  const float* LQ = (const float*)d_in[4];
  const float* LR = (const float*)d_in[5];
  const float* W1 = (const float*)d_in[6];
  const float* b1 = (const float*)d_in[7];
  const float* W2 = (const float*)d_in[8];
  const float* b2 = (const float*)d_in[9];
  float* out = (float*)d_out;
  float* wpk = (float*)d_ws;
  int B = in_sizes[0] / 6;

  hipLaunchKernelGGL(pack_weights, dim3(1), dim3(64), 0, stream, W1, b1, W2, wpk);
  int block = 256;
  long long threads = (long long)B * 16;
  int grid = (int)((threads + block - 1) / block);
  hipLaunchKernelGGL(ukf_kernel, dim3(grid), dim3(block), 0, stream,
                     x, P, u, y, LQ, LR, b2, wpk, out, B);
}

// Round 3
// 440.073 us; speedup vs baseline: 1.0428x; 1.0428x over previous
//
#include <hip/hip_runtime.h>
#include <math.h>

typedef __attribute__((ext_vector_type(8))) short bf16x8;
typedef __attribute__((ext_vector_type(4))) float f32x4;

#define TRI(i,j) (((i)*((i)+1))/2 + (j))

#if __has_builtin(__builtin_amdgcn_exp2f)
#define EXP2F(x) __builtin_amdgcn_exp2f(x)
#else
#define EXP2F(x) exp2f(x)
#endif

#define CSC 2.8853900817779268f   /* 2*log2(e): folded into W1,b1 so tanh uses exp2 */

static __device__ __forceinline__ float tanh_scaled(float v) {
  // v = 2*log2e*z  ->  tanh(z) = 1 - 2/(2^v + 1); overflow-safe (inf -> 1, 0 -> -1)
  float e = EXP2F(v);
  return fmaf(-2.0f, __builtin_amdgcn_rcpf(e + 1.0f), 1.0f);
}
static __device__ __forceinline__ unsigned short f2b(float f) {
  union { float f; unsigned u; } v; v.f = f;
  unsigned r = v.u + 0x7FFFu + ((v.u >> 16) & 1u);   // RNE f32->bf16
  return (unsigned short)(r >> 16);
}
static __device__ __forceinline__ unsigned pk2(float lo, float hi) {
  return (unsigned)f2b(lo) | ((unsigned)f2b(hi) << 16);
}

// ---- setup: per-lane MFMA weight fragments into d_ws (176 B per lane) ----
// [0..63]   A1 tiles t=0..3 : A[m=16t+r][k=j(feat)] = CSC*W1[j][16t+r]  (q==0 else 0)
// [64..95]  A2 kk=0..1      : A[m=r(feat)][k=kk*32+q*8+j(hidden)] = W2[hid][r]
// [96..159] c1 tiles        : bias rows: CSC*b1[16t+4q+g]
// [160..175] c2             : b2[4q+g] (feat<6 else 0)
__global__ void pack_frags(const float* __restrict__ W1, const float* __restrict__ b1,
                           const float* __restrict__ W2, const float* __restrict__ b2,
                           char* __restrict__ ws) {
  int lane = threadIdx.x;            // 0..63
  int r = lane & 15, q = lane >> 4;
  unsigned* wpA1 = (unsigned*)(ws + lane * 176);
  unsigned* wpA2 = (unsigned*)(ws + lane * 176 + 64);
  float*    wpc1 = (float*)   (ws + lane * 176 + 96);
  float*    wpc2 = (float*)   (ws + lane * 176 + 160);
#pragma unroll
  for (int t = 0; t < 4; ++t) {
    float wv[8];
#pragma unroll
    for (int j = 0; j < 8; ++j) wv[j] = (q == 0) ? CSC * W1[j * 64 + 16 * t + r] : 0.0f;
#pragma unroll
    for (int p = 0; p < 4; ++p) wpA1[t * 4 + p] = pk2(wv[2 * p], wv[2 * p + 1]);
  }
#pragma unroll
  for (int kk = 0; kk < 2; ++kk) {
    float wv[8];
#pragma unroll
    for (int j = 0; j < 8; ++j) {
      int hid = kk * 32 + q * 8 + j;
      wv[j] = (r < 6) ? W2[hid * 6 + r] : 0.0f;
    }
#pragma unroll
    for (int p = 0; p < 4; ++p) wpA2[kk * 4 + p] = pk2(wv[2 * p], wv[2 * p + 1]);
  }
#pragma unroll
  for (int t = 0; t < 4; ++t)
#pragma unroll
    for (int g = 0; g < 4; ++g) wpc1[t * 4 + g] = CSC * b1[16 * t + 4 * q + g];
#pragma unroll
  for (int g = 0; g < 4; ++g) { int idx = 4 * q + g; wpc2[g] = (idx < 6) ? b2[idx] : 0.0f; }
}

// One wave = one batch. Per-wave LDS: Hs bf16[16 sigma][72] (2304 B) + dxT f32[16][16] (1024 B).
__launch_bounds__(256, 3)
__global__ void ukf_mfma(const float* __restrict__ gx,
                         const float* __restrict__ gP,
                         const float* __restrict__ gu,
                         const float* __restrict__ gy,
                         const float* __restrict__ gLQ,
                         const float* __restrict__ gLR,
                         const char*  __restrict__ ws,
                         float* __restrict__ out, int B) {
  __shared__ f32x4 ldsv[4][208];                       // 4 waves x 3328 B, 16B aligned
  int lane = threadIdx.x & 63;
  int wid  = threadIdx.x >> 6;
  int b    = blockIdx.x * 4 + wid;
  if (b >= B) return;
  int r = lane & 15, q = lane >> 4;
  char*  base = (char*)&ldsv[wid][0];
  unsigned* Hw  = (unsigned*)base;                     // Hs as u32 words
  float*    dxT = (float*)(base + 2304);

  // ---- weight fragments from ws ----
  const char* wp = ws + lane * 176;
  bf16x8 A1v[4], A2v[2];
  f32x4  c1v[4], c2i;
#pragma unroll
  for (int t = 0; t < 4; ++t) A1v[t] = ((const bf16x8*)wp)[t];
#pragma unroll
  for (int kk = 0; kk < 2; ++kk) A2v[kk] = ((const bf16x8*)(wp + 64))[kk];
#pragma unroll
  for (int t = 0; t < 4; ++t) c1v[t] = ((const f32x4*)(wp + 96))[t];
  c2i = *((const f32x4*)(wp + 160));

  // ---- per-batch inputs (wave-uniform addresses) ----
  float x0[6];
  {
    const float* xb = gx + b * 6;
    float2 t0 = *(const float2*)(xb);
    float2 t1 = *(const float2*)(xb + 2);
    float2 t2 = *(const float2*)(xb + 4);
    x0[0]=t0.x; x0[1]=t0.y; x0[2]=t1.x; x0[3]=t1.y; x0[4]=t2.x; x0[5]=t2.y;
  }
  float2 uu = *(const float2*)(gu + b * 2);
  float yy0, yy1, yy2;
  { const float* yb = gy + b * 3; yy0 = yb[0]; yy1 = yb[1]; yy2 = yb[2]; }

  // ---- cholesky of 0.75*(P+P^T)+1e-5 I (all lanes redundant) ----
  float Lt[21];
  {
    float Pf[36];
    const float4* p4 = (const float4*)(gP + b * 36);
#pragma unroll
    for (int qq = 0; qq < 9; ++qq) {
      float4 v = p4[qq];
      Pf[qq*4+0]=v.x; Pf[qq*4+1]=v.y; Pf[qq*4+2]=v.z; Pf[qq*4+3]=v.w;
    }
    float basem[21];
#pragma unroll
    for (int i = 0; i < 6; ++i)
#pragma unroll
      for (int j = 0; j <= i; ++j)
        basem[TRI(i,j)] = 0.75f * (Pf[i*6+j] + Pf[j*6+i]) + ((i==j) ? 1e-5f : 0.0f);
#pragma unroll
    for (int k = 0; k < 6; ++k) {
      float s = basem[TRI(k,k)];
#pragma unroll
      for (int m2 = 0; m2 < k; ++m2) s = fmaf(-Lt[TRI(k,m2)], Lt[TRI(k,m2)], s);
      float d = sqrtf(s);
      Lt[TRI(k,k)] = d;
      float inv = 1.0f / d;
#pragma unroll
      for (int i = k + 1; i < 6; ++i) {
        float s2 = basem[TRI(i,k)];
#pragma unroll
        for (int m2 = 0; m2 < k; ++m2) s2 = fmaf(-Lt[TRI(i,m2)], Lt[TRI(k,m2)], s2);
        Lt[TRI(i,k)] = s2 * inv;
      }
    }
  }

  // ---- this lane's sigma column (r = sigma index) ----
  float sgn = (r == 0 || r > 12) ? 0.0f : ((r <= 6) ? 1.0f : -1.0f);
  int   c   = (r >= 1 && r <= 6) ? (r - 1) : ((r >= 7 && r <= 12) ? (r - 7) : 0);
  float Lcol[8];
#pragma unroll
  for (int f = 0; f < 6; ++f) {
    float v = 0.0f;
#pragma unroll
    for (int k = 0; k <= f; ++k) v = (c == k) ? Lt[TRI(f,k)] : v;
    Lcol[f] = v;
  }
  Lcol[6] = 0.0f; Lcol[7] = 0.0f;
  float xs0 = x0[0] + sgn*Lcol[0], xs1 = x0[1] + sgn*Lcol[1], xs2 = x0[2] + sgn*Lcol[2];
  float xs3 = x0[3] + sgn*Lcol[3], xs4 = x0[4] + sgn*Lcol[4], xs5 = x0[5] + sgn*Lcol[5];
  unsigned uu_pk = pk2(uu.x, uu.y);

  // ---- RK4: layer1 (4 mfma) -> tanh -> LDS -> layer2 (2 mfma) ----
  f32x4 d2v;
  float ksum[4] = {0.f, 0.f, 0.f, 0.f};
#pragma unroll 1
  for (int st = 0; st < 4; ++st) {
    float kf0=0.f,kf1=0.f,kf2=0.f,kf3=0.f,kf4=0.f,kf5=0.f;
    if (st > 0) {
      kf0 = d2v[0]; kf1 = d2v[1]; kf2 = d2v[2]; kf3 = d2v[3];      // feats 0-3 at q==0 lanes
      kf4 = __shfl(d2v[0], (lane & 15) + 16, 64);                   // feat 4 (row 4 = q1,reg0)
      kf5 = __shfl(d2v[1], (lane & 15) + 16, 64);                   // feat 5
    }
    float cin = (st == 3) ? 0.01f : 0.005f;
    float xi0 = fmaf(cin, kf0, xs0), xi1 = fmaf(cin, kf1, xs1), xi2 = fmaf(cin, kf2, xs2);
    float xi3 = fmaf(cin, kf3, xs3), xi4 = fmaf(cin, kf4, xs4), xi5 = fmaf(cin, kf5, xs5);
    union { bf16x8 v; unsigned u[4]; } bu;
    bu.u[0] = (q == 0) ? pk2(xi0, xi1) : 0u;
    bu.u[1] = (q == 0) ? pk2(xi2, xi3) : 0u;
    bu.u[2] = (q == 0) ? pk2(xi4, xi5) : 0u;
    bu.u[3] = (q == 0) ? uu_pk : 0u;

    // layer1 transposed: D1t[hidden][sigma]
#pragma unroll
    for (int t = 0; t < 4; ++t) {
      f32x4 d1 = __builtin_amdgcn_mfma_f32_16x16x32_bf16(A1v[t], bu.v, c1v[t], 0, 0, 0);
      float h0 = tanh_scaled(d1[0]);
      float h1 = tanh_scaled(d1[1]);
      float h2 = tanh_scaled(d1[2]);
      float h3 = tanh_scaled(d1[3]);
      // Hs[sigma=r][hidden=16t+4q+reg], bf16, row stride 72 (=36 words)
      Hw[r * 36 + 8 * t + 2 * q + 0] = pk2(h0, h1);
      Hw[r * 36 + 8 * t + 2 * q + 1] = pk2(h2, h3);
    }
    // layer2 A/B shared fragment: lane(sigma=r, k=hidden q*8+j)
    bf16x8 Hf0 = *((const bf16x8*)(base + r * 144 +      q * 16));
    bf16x8 Hf1 = *((const bf16x8*)(base + r * 144 + 64 + q * 16));
    d2v = __builtin_amdgcn_mfma_f32_16x16x32_bf16(A2v[0], Hf0, c2i, 0, 0, 0);
    d2v = __builtin_amdgcn_mfma_f32_16x16x32_bf16(A2v[1], Hf1, d2v, 0, 0, 0);

    float wks = (st == 0 || st == 3) ? 1.0f : 2.0f;
#pragma unroll
    for (int g = 0; g < 4; ++g) ksum[g] = fmaf(wks, d2v[g], ksum[g]);
  }

  // ---- deltas: dl = sgn*Lcol[feat] + dt/6 * ksum  (feat = 4q+g; x0 cancels) ----
  const float dt6 = 0.01f / 6.0f;
#pragma unroll
  for (int g = 0; g < 4; ++g) {
    float Lc = (q == 0) ? Lcol[g] : ((q == 1) ? Lcol[4 + g] : 0.0f);
    float dl = fmaf(dt6, ksum[g], sgn * Lc);
    dxT[(4 * q + g) * 16 + r] = dl;       // dxT[feat][sigma]
  }

  // ---- moments via one mfma: A=[wc*dx ; wc ; wm ; 0], B=dx ----
  union { bf16x8 v; unsigned u[4]; } am, bm;
  {
    int roff = r * 16 + (q & 1) * 8;
    f32x4 dxa = *((const f32x4*)(dxT + roff));
    f32x4 dxb = *((const f32x4*)(dxT + roff + 4));
    float dxv[8] = {dxa[0],dxa[1],dxa[2],dxa[3],dxb[0],dxb[1],dxb[2],dxb[3]};
    float av[8], bv[8];
#pragma unroll
    for (int j = 0; j < 8; ++j) {
      float wcv = 0.0f, wmv = 0.0f;
      if (q < 2) {
        int sv = q * 8 + j;
        wcv = (sv == 0) ? -0.25f : ((sv <= 12) ? (1.0f/3.0f) : 0.0f);
        wmv = (sv == 0) ? -3.0f  : ((sv <= 12) ? (1.0f/3.0f) : 0.0f);
      }
      bv[j] = (q < 2) ? dxv[j] : 0.0f;
      av[j] = (r < 6) ? wcv * bv[j] : ((r == 6) ? wcv : ((r == 7) ? wmv : 0.0f));
    }
#pragma unroll
    for (int p = 0; p < 4; ++p) { am.u[p] = pk2(av[2*p], av[2*p+1]); bm.u[p] = pk2(bv[2*p], bv[2*p+1]); }
  }
  f32x4 zz = {0.0f, 0.0f, 0.0f, 0.0f};
  f32x4 Dm = __builtin_amdgcn_mfma_f32_16x16x32_bf16(am.v, bm.v, zz, 0, 0, 0);

  // ---- broadcast U(21), cb(6), db(6): D[row][col] at lane 16*(row>>2)+col, reg row&3
  float U[21], cb[6], db[6];
#pragma unroll
  for (int i = 0; i < 6; ++i)
#pragma unroll
    for (int j = 0; j <= i; ++j) {
      int src = ((i >> 2) << 4) + j;
      float v = (i & 3) == 0 ? __shfl(Dm[0], src, 64)
              : (i & 3) == 1 ? __shfl(Dm[1], src, 64)
              : (i & 3) == 2 ? __shfl(Dm[2], src, 64)
                             : __shfl(Dm[3], src, 64);
      U[TRI(i,j)] = v;
    }
#pragma unroll
  for (int j = 0; j < 6; ++j) {
    cb[j] = __shfl(Dm[2], 16 + j, 64);   // row 6
    db[j] = __shfl(Dm[3], 16 + j, 64);   // row 7
  }

  // ---- uniform Q, R ----
  float Qm[21];
#pragma unroll
  for (int i = 0; i < 6; ++i)
#pragma unroll
    for (int j = 0; j <= i; ++j) {
      float s = (i==j) ? 1e-7f : 0.0f;
#pragma unroll
      for (int k = 0; k <= j; ++k) s = fmaf(gLQ[i*6+k], gLQ[j*6+k], s);
      Qm[TRI(i,j)] = s;
    }
  float Rm[6];
#pragma unroll
  for (int i = 0; i < 3; ++i)
#pragma unroll
    for (int j = 0; j <= i; ++j) {
      float s = (i==j) ? 1e-7f : 0.0f;
#pragma unroll
      for (int k = 0; k <= j; ++k) s = fmaf(gLR[i*3+k], gLR[j*3+k], s);
      Rm[TRI(i,j)] = s;
    }

  // ---- epilogue (all lanes redundant) ----
  float xp[6];
#pragma unroll
  for (int i = 0; i < 6; ++i) xp[i] = x0[i] + db[i];
  float D[21];
#pragma unroll
  for (int i = 0; i < 6; ++i)
#pragma unroll
    for (int j = 0; j <= i; ++j) {
      float v = U[TRI(i,j)];
      v -= cb[i] * db[j];
      v -= db[i] * cb[j];
      v = fmaf(3.75f * db[i], db[j], v);
      D[TRI(i,j)] = v;
    }
  float s00 = D[TRI(0,0)] + Rm[TRI(0,0)];
  float s10 = D[TRI(1,0)] + Rm[TRI(1,0)];
  float s11 = D[TRI(1,1)] + Rm[TRI(1,1)];
  float s20 = D[TRI(2,0)] + Rm[TRI(2,0)];
  float s21 = D[TRI(2,1)] + Rm[TRI(2,1)];
  float s22 = D[TRI(2,2)] + Rm[TRI(2,2)];
  float a00 = s00 + 1e-5f, a11 = s11 + 1e-5f, a22 = s22 + 1e-5f;
  float a10 = s10, a20 = s20, a21 = s21;
  float adj00 = a11*a22 - a21*a21;
  float adj01 = a20*a21 - a10*a22;
  float adj02 = a10*a21 - a11*a20;
  float adj11 = a00*a22 - a20*a20;
  float adj12 = a10*a20 - a00*a21;
  float adj22 = a00*a11 - a10*a10;
  float det  = a00*adj00 + a10*adj01 + a20*adj02;
  float idet = 1.0f / det;
  float I00 = adj00*idet, I01 = adj01*idet, I02 = adj02*idet;
  float I11 = adj11*idet, I12 = adj12*idet, I22 = adj22*idet;

#define DS(i,j) ((i) >= (j) ? D[TRI(i,j)] : D[TRI(j,i)])
  float K_[18];
#pragma unroll
  for (int i = 0; i < 6; ++i) {
    float c0 = DS(i,0), c1 = DS(i,1), c2 = DS(i,2);
    K_[i*3+0] = c0*I00 + c1*I01 + c2*I02;
    K_[i*3+1] = c0*I01 + c1*I11 + c2*I12;
    K_[i*3+2] = c0*I02 + c1*I12 + c2*I22;
  }
  float inn0 = yy0 - xp[0], inn1 = yy1 - xp[1], inn2 = yy2 - xp[2];
  float xu[6];
#pragma unroll
  for (int i = 0; i < 6; ++i)
    xu[i] = xp[i] + K_[i*3]*inn0 + K_[i*3+1]*inn1 + K_[i*3+2]*inn2;

  float KS[18];
#pragma unroll
  for (int i = 0; i < 6; ++i) {
    float k0 = K_[i*3], k1 = K_[i*3+1], k2 = K_[i*3+2];
    KS[i*3+0] = k0*s00 + k1*s10 + k2*s20;
    KS[i*3+1] = k0*s10 + k1*s11 + k2*s21;
    KS[i*3+2] = k0*s20 + k1*s21 + k2*s22;
  }
  float Pu[21];
#pragma unroll
  for (int i = 0; i < 6; ++i)
#pragma unroll
    for (int j = 0; j <= i; ++j) {
      float v = D[TRI(i,j)] + Qm[TRI(i,j)];
      v -= KS[i*3]*K_[j*3] + KS[i*3+1]*K_[j*3+1] + KS[i*3+2]*K_[j*3+2];
      Pu[TRI(i,j)] = v + ((i==j) ? 1e-4f : 0.0f);
    }

  // ---- stores: wave leader ----
  if (lane == 0) {
    float* o_xu = out;
    float* o_Pu = out + (size_t)6  * B;
    float* o_xp = out + (size_t)42 * B;
    float* o_Pp = out + (size_t)48 * B;
    float* o_yp = out + (size_t)84 * B;
    float* o_S  = out + (size_t)87 * B;
    float* o_K  = out + (size_t)96 * B;
    {
      float* p = o_xu + b * 6;
      ((float2*)p)[0] = make_float2(xu[0], xu[1]);
      ((float2*)p)[1] = make_float2(xu[2], xu[3]);
      ((float2*)p)[2] = make_float2(xu[4], xu[5]);
    }
    {
      float* p = o_Pu + b * 36;
#pragma unroll
      for (int i = 0; i < 6; ++i)
#pragma unroll
        for (int j = 0; j < 6; j += 2) {
          float v0 = (i>=j)   ? Pu[TRI(i,j)]   : Pu[TRI(j,i)];
          float v1 = (i>=j+1) ? Pu[TRI(i,j+1)] : Pu[TRI(j+1,i)];
          *(float2*)(p + i*6 + j) = make_float2(v0, v1);
        }
    }
    {
      float* p = o_xp + b * 6;
      ((float2*)p)[0] = make_float2(xp[0], xp[1]);
      ((float2*)p)[1] = make_float2(xp[2], xp[3]);
      ((float2*)p)[2] = make_float2(xp[4], xp[5]);
    }
    {
      float* p = o_Pp + b * 36;
#pragma unroll
      for (int i = 0; i < 6; ++i)
#pragma unroll
        for (int j = 0; j < 6; j += 2) {
          float v0 = ((i>=j)   ? D[TRI(i,j)]   : D[TRI(j,i)])   + ((i>=j)   ? Qm[TRI(i,j)]   : Qm[TRI(j,i)]);
          float v1 = ((i>=j+1) ? D[TRI(i,j+1)] : D[TRI(j+1,i)]) + ((i>=j+1) ? Qm[TRI(i,j+1)] : Qm[TRI(j+1,i)]);
          *(float2*)(p + i*6 + j) = make_float2(v0, v1);
        }
    }
    {
      float* p = o_yp + b * 3;
      p[0] = xp[0]; p[1] = xp[1]; p[2] = xp[2];
    }
    {
      float* p = o_S + b * 9;
      p[0]=s00; p[1]=s10; p[2]=s20;
      p[3]=s10; p[4]=s11; p[5]=s21;
      p[6]=s20; p[7]=s21; p[8]=s22;
    }
    {
      float* p = o_K + b * 18;
#pragma unroll
      for (int i = 0; i < 9; ++i)
        ((float2*)p)[i] = make_float2(K_[i*2], K_[i*2+1]);
    }
  }
}

extern "C" void kernel_launch(void* const* d_in, const int* in_sizes, int n_in,
                              void* d_out, int out_size, void* d_ws, size_t ws_size,
                              hipStream_t stream) {
  const float* x  = (const float*)d_in[0];
  const float* P  = (const float*)d_in[1];
  const float* u  = (const float*)d_in[2];
  const float* y  = (const float*)d_in[3];
  const float* LQ = (const float*)d_in[4];
  const float* LR = (const float*)d_in[5];
  const float* W1 = (const float*)d_in[6];
  const float* b1 = (const float*)d_in[7];
  const float* W2 = (const float*)d_in[8];
  const float* b2 = (const float*)d_in[9];
  float* out = (float*)d_out;
  char*  ws  = (char*)d_ws;
  int B = in_sizes[0] / 6;

  hipLaunchKernelGGL(pack_frags, dim3(1), dim3(64), 0, stream, W1, b1, W2, b2, ws);
  int blocks = (B + 3) / 4;     // 1 wave per batch, 4 waves per block
  hipLaunchKernelGGL(ukf_mfma, dim3(blocks), dim3(256), 0, stream,
                     x, P, u, y, LQ, LR, (const char*)ws, out, B);
}

// Round 4
// 288.333 us; speedup vs baseline: 1.5915x; 1.5263x over previous
//
#include <hip/hip_runtime.h>
#include <math.h>

typedef __attribute__((ext_vector_type(8)))  short bf16x8;
typedef __attribute__((ext_vector_type(4)))  float f32x4;
typedef __attribute__((ext_vector_type(16))) float f32x16;
typedef __attribute__((ext_vector_type(2)))  float f32x2;

#define TRI(i,j) (((i)*((i)+1))/2 + (j))
#define ONE3 0.3333333333333333f
#define QOFF 6144   /* byte offset of Q/R constants in ws (after 64*96B frags) */

// RNE f32->bf16 (used where precision matters: moment fragments)
static __device__ __forceinline__ unsigned short f2b(float f) {
  union { float f; unsigned u; } v; v.f = f;
  unsigned r = v.u + 0x7FFFu + ((v.u >> 16) & 1u);
  return (unsigned short)(r >> 16);
}
static __device__ __forceinline__ unsigned pk2(float lo, float hi) {
  return (unsigned)f2b(lo) | ((unsigned)f2b(hi) << 16);
}
// truncating f32x2 -> packed bf16x2 in ONE v_perm_b32 (dt-damped NN path only)
static __device__ __forceinline__ unsigned pk2t(float lo, float hi) {
  return __builtin_amdgcn_perm(__float_as_uint(hi), __float_as_uint(lo), 0x07060302u);
}

// odd deg-7 tanh approx on [-3,3] (max err ~0.02; output is dt-damped so ~1e-3 impact)
#define TC0 0.970866f
#define TC1 (-0.217815f)
#define TC2 0.028904f
#define TC3 (-0.0014079f)

static __device__ __forceinline__ unsigned tanh2_pk(float a, float b) {
#if __has_builtin(__builtin_elementwise_fma) && __has_builtin(__builtin_elementwise_min) && __has_builtin(__builtin_elementwise_max)
  f32x2 z; z[0] = a; z[1] = b;
  f32x2 lo = {-3.0f, -3.0f}, hi = {3.0f, 3.0f};
  f32x2 k3 = {TC3, TC3}, k2 = {TC2, TC2}, k1 = {TC1, TC1}, k0 = {TC0, TC0};
  z = __builtin_elementwise_max(z, lo);
  z = __builtin_elementwise_min(z, hi);
  f32x2 t = z * z;
  f32x2 p = __builtin_elementwise_fma(t, k3, k2);
  p = __builtin_elementwise_fma(p, t, k1);
  p = __builtin_elementwise_fma(p, t, k0);
  f32x2 r = z * p;
  return pk2t(r[0], r[1]);
#else
  float za = fminf(fmaxf(a, -3.0f), 3.0f);
  float zb = fminf(fmaxf(b, -3.0f), 3.0f);
  float ta = za * za, tb = zb * zb;
  float pa = fmaf(fmaf(fmaf(TC3, ta, TC2), ta, TC1), ta, TC0);
  float pb = fmaf(fmaf(fmaf(TC3, tb, TC2), tb, TC1), tb, TC0);
  return pk2t(za * pa, zb * pb);
#endif
}

// ---- setup: per-lane 32x32x16 MFMA weight fragments (96B/lane) + Q/R consts ----
// A1[t] (t=0,1): A[m=32t+(lane&31)][k=8u+j]: u=0 -> W1 rows 0..7; u=1 -> k=8 bias row b1, rest 0
// A2[kq] (kq=0..3): A[m=feat(lane&31)][k=8u+j] = W2[16kq+8u+j][feat] (feat<6 else 0)
__global__ void pack_frags(const float* __restrict__ W1, const float* __restrict__ b1,
                           const float* __restrict__ W2,
                           const float* __restrict__ LQ, const float* __restrict__ LR,
                           char* __restrict__ ws) {
  int lane = threadIdx.x;          // 0..63
  int mr = lane & 31, u = lane >> 5;
  unsigned* A1 = (unsigned*)(ws + lane * 96);
  unsigned* A2 = (unsigned*)(ws + lane * 96 + 32);
#pragma unroll
  for (int t = 0; t < 2; ++t) {
    int h = 32 * t + mr;
    if (u == 0) {
#pragma unroll
      for (int p = 0; p < 4; ++p)
        A1[t * 4 + p] = pk2(W1[(2 * p) * 64 + h], W1[(2 * p + 1) * 64 + h]);
    } else {
      A1[t * 4 + 0] = pk2(b1[h], 0.0f);
      A1[t * 4 + 1] = 0u; A1[t * 4 + 2] = 0u; A1[t * 4 + 3] = 0u;
    }
  }
#pragma unroll
  for (int kq = 0; kq < 4; ++kq) {
#pragma unroll
    for (int p = 0; p < 4; ++p) {
      float lo = (mr < 6) ? W2[(16 * kq + 8 * u + 2 * p) * 6 + mr] : 0.0f;
      float hi = (mr < 6) ? W2[(16 * kq + 8 * u + 2 * p + 1) * 6 + mr] : 0.0f;
      A2[kq * 4 + p] = pk2(lo, hi);
    }
  }
  if (lane == 0) {
    float* qo = (float*)(ws + QOFF);
    for (int i = 0; i < 6; ++i)
      for (int j = 0; j <= i; ++j) {
        float s = (i == j) ? 1e-7f : 0.0f;
        for (int k = 0; k <= j; ++k) s = fmaf(LQ[i * 6 + k], LQ[j * 6 + k], s);
        qo[TRI(i, j)] = s;
      }
    for (int i = 0; i < 3; ++i)
      for (int j = 0; j <= i; ++j) {
        float s = (i == j) ? 1e-7f : 0.0f;
        for (int k = 0; k <= j; ++k) s = fmaf(LR[i * 3 + k], LR[j * 3 + k], s);
        qo[21 + TRI(i, j)] = s;
      }
  }
}

// One wave = TWO batches. Columns c=lane&31: c<16 -> batch 2p, c>=16 -> batch 2p+1.
// Layer1/2 via 32x32x16 MFMA; layer2 B-frags from D1 C-layout via shfl_xor(32) partner
// exchange (no LDS in K-loop). Moments via 2x 16x16x32 MFMA. Epilogue per half-wave.
__launch_bounds__(256, 4)
__global__ void ukf_mfma2(const float* __restrict__ gx,
                          const float* __restrict__ gP,
                          const float* __restrict__ gu,
                          const float* __restrict__ gy,
                          const float* __restrict__ gb2,
                          const char*  __restrict__ ws,
                          float* __restrict__ out, int B) {
  __shared__ f32x4 ldsv[4][176];   // per wave: dx[32 cols][17] (544 f32) + Ubuf 2x64 f32
  int lane = threadIdx.x & 63;
  int wid  = threadIdx.x >> 6;
  int p    = blockIdx.x * 4 + wid;           // batch pair index
  if (2 * p >= B) return;
  int u   = lane >> 5;                        // k-half for 32x32 MFMA
  int c   = lane & 31;                        // column (sigma, batch-half)
  int q16 = lane >> 4, m16 = lane & 15;       // 16x16 MFMA coords (moments)
  int bc  = 2 * p + ((lane >> 4) & 1);        // this column's batch
  int be  = 2 * p + u;                        // this half-wave's epilogue batch
  float* dxs = (float*)&ldsv[wid][0];

  // ---- weight fragments ----
  const char* wp = ws + lane * 96;
  bf16x8 A1v0 = *((const bf16x8*)wp);
  bf16x8 A1v1 = *((const bf16x8*)(wp + 16));
  bf16x8 A2v[4];
#pragma unroll
  for (int kq = 0; kq < 4; ++kq) A2v[kq] = *((const bf16x8*)(wp + 32 + kq * 16));
  float b2r[6];
#pragma unroll
  for (int i = 0; i < 6; ++i) b2r[i] = gb2[i];

  // ---- per-column inputs ----
  float x0c[6];
  {
    const float* xb = gx + bc * 6;
    float2 t0 = *(const float2*)(xb);
    float2 t1 = *(const float2*)(xb + 2);
    float2 t2 = *(const float2*)(xb + 4);
    x0c[0]=t0.x; x0c[1]=t0.y; x0c[2]=t1.x; x0c[3]=t1.y; x0c[4]=t2.x; x0c[5]=t2.y;
  }
  float2 uu = *(const float2*)(gu + bc * 2);
  unsigned uu_pk = pk2(uu.x, uu.y);

  // ---- cholesky of 0.75*(P+P^T)+1e-5 I for this column's batch ----
  float Lt[21];
  {
    float Pf[36];
    const float4* p4 = (const float4*)(gP + bc * 36);
#pragma unroll
    for (int qq = 0; qq < 9; ++qq) {
      float4 v = p4[qq];
      Pf[qq*4+0]=v.x; Pf[qq*4+1]=v.y; Pf[qq*4+2]=v.z; Pf[qq*4+3]=v.w;
    }
    float basem[21];
#pragma unroll
    for (int i = 0; i < 6; ++i)
#pragma unroll
      for (int j = 0; j <= i; ++j)
        basem[TRI(i,j)] = 0.75f * (Pf[i*6+j] + Pf[j*6+i]) + ((i==j) ? 1e-5f : 0.0f);
#pragma unroll
    for (int k = 0; k < 6; ++k) {
      float s = basem[TRI(k,k)];
#pragma unroll
      for (int m2 = 0; m2 < k; ++m2) s = fmaf(-Lt[TRI(k,m2)], Lt[TRI(k,m2)], s);
      float d = sqrtf(s);
      Lt[TRI(k,k)] = d;
      float inv = 1.0f / d;
#pragma unroll
      for (int i = k + 1; i < 6; ++i) {
        float s2 = basem[TRI(i,k)];
#pragma unroll
        for (int m2 = 0; m2 < k; ++m2) s2 = fmaf(-Lt[TRI(i,m2)], Lt[TRI(k,m2)], s2);
        Lt[TRI(i,k)] = s2 * inv;
      }
    }
  }

  // ---- sigma column state ----
  int   sidx = c & 15;
  float sgn = (sidx == 0 || sidx > 12) ? 0.0f : ((sidx <= 6) ? 1.0f : -1.0f);
  int   cc  = (sidx >= 1 && sidx <= 6) ? (sidx - 1) : ((sidx >= 7) ? (sidx - 7) : 0);
  float sgnL[6], xs[6];
#pragma unroll
  for (int f = 0; f < 6; ++f) {
    float v = 0.0f;
#pragma unroll
    for (int k = 0; k <= f; ++k) v = (cc == k) ? Lt[TRI(f,k)] : v;
    sgnL[f] = sgn * v;
    xs[f]   = x0c[f] + sgnL[f];
  }

  // ---- RK4 ----
  float kf[6]   = {0,0,0,0,0,0};
  float ksum[6] = {0,0,0,0,0,0};
#pragma unroll
  for (int st = 0; st < 4; ++st) {
    const float cin = (st == 3) ? 0.01f : 0.005f;   // st==0 nulled by kf=0
    float xi[6];
#pragma unroll
    for (int f = 0; f < 6; ++f) xi[f] = fmaf(cin, kf[f], xs[f]);
    // layer1 B-fragment: u=0 lanes carry state (k=0..7), u=1 carry bias one-hot (k=8)
    union { bf16x8 v; unsigned w[4]; } bx;
    bx.w[0] = u ? 0x00003F80u : pk2t(xi[0], xi[1]);
    bx.w[1] = u ? 0u          : pk2t(xi[2], xi[3]);
    bx.w[2] = u ? 0u          : pk2t(xi[4], xi[5]);
    bx.w[3] = u ? 0u          : uu_pk;
    f32x16 z16;
#pragma unroll
    for (int i = 0; i < 16; ++i) z16[i] = 0.0f;
    f32x16 d1a = __builtin_amdgcn_mfma_f32_32x32x16_bf16(A1v0, bx.v, z16, 0, 0, 0);
    f32x16 d1b = __builtin_amdgcn_mfma_f32_32x32x16_bf16(A1v1, bx.v, z16, 0, 0, 0);
    unsigned Hpk[16];
#pragma unroll
    for (int pr = 0; pr < 8; ++pr) Hpk[pr]     = tanh2_pk(d1a[2*pr], d1a[2*pr+1]);
#pragma unroll
    for (int pr = 0; pr < 8; ++pr) Hpk[8 + pr] = tanh2_pk(d1b[2*pr], d1b[2*pr+1]);
    // layer2: 4 K-blocks; B-frag rows via partner exchange (shfl_xor 32)
    f32x16 d2 = z16;
#pragma unroll
    for (int kq = 0; kq < 4; ++kq) {
      int base = 8 * (kq >> 1) + 4 * (kq & 1);
      unsigned vA = u ? Hpk[base + 0] : Hpk[base + 2];
      unsigned vB = u ? Hpk[base + 1] : Hpk[base + 3];
      unsigned rA = __shfl_xor(vA, 32, 64);
      unsigned rB = __shfl_xor(vB, 32, 64);
      union { bf16x8 v; unsigned w[4]; } bh;
      bh.w[0] = u ? rA : Hpk[base + 0];
      bh.w[1] = u ? rB : Hpk[base + 1];
      bh.w[2] = u ? Hpk[base + 2] : rA;
      bh.w[3] = u ? Hpk[base + 3] : rB;
      d2 = __builtin_amdgcn_mfma_f32_32x32x16_bf16(A2v[kq], bh.v, d2, 0, 0, 0);
    }
    // extract this column's k (feats 0..5): rows 0-3 in u=0 regs0-3, rows 4-5 in u=1 regs0-1
    float e0 = __shfl_xor(d2[0], 32, 64);
    float e1 = __shfl_xor(d2[1], 32, 64);
    float e2 = __shfl_xor(d2[2], 32, 64);
    float e3 = __shfl_xor(d2[3], 32, 64);
    kf[0] = (u ? e0 : d2[0]) + b2r[0];
    kf[1] = (u ? e1 : d2[1]) + b2r[1];
    kf[2] = (u ? e2 : d2[2]) + b2r[2];
    kf[3] = (u ? e3 : d2[3]) + b2r[3];
    kf[4] = (u ? d2[0] : e0) + b2r[4];
    kf[5] = (u ? d2[1] : e1) + b2r[5];
    const float wks = (st == 0 || st == 3) ? 1.0f : 2.0f;
#pragma unroll
    for (int f = 0; f < 6; ++f) ksum[f] = fmaf(wks, kf[f], ksum[f]);
  }

  // ---- deltas -> LDS (dx[col][feat], stride 17: conflict-free) ----
  const float dt6 = 0.01f / 6.0f;
  float dl[6];
#pragma unroll
  for (int f = 0; f < 6; ++f) dl[f] = fmaf(dt6, ksum[f], sgnL[f]);
  if (u == 0) {
#pragma unroll
    for (int f = 0; f < 6; ++f) dxs[c * 17 + f] = dl[f];
  }

  // epilogue inputs (issue loads early)
  float x0e[6];
  {
    const float* xb = gx + be * 6;
    float2 t0 = *(const float2*)(xb);
    float2 t1 = *(const float2*)(xb + 2);
    float2 t2 = *(const float2*)(xb + 4);
    x0e[0]=t0.x; x0e[1]=t0.y; x0e[2]=t1.x; x0e[3]=t1.y; x0e[4]=t2.x; x0e[5]=t2.y;
  }
  const float* yb = gy + be * 3;
  float yy0 = yb[0], yy1 = yb[1], yy2 = yb[2];

  // ---- moments: two 16x16x32 MFMAs (batch-masked A weights), shared B = dx ----
  float dxv[8];
#pragma unroll
  for (int j = 0; j < 8; ++j) dxv[j] = dxs[(8 * q16 + j) * 17 + m16];
  float wc0[8], wc1[8];
#pragma unroll
  for (int j = 0; j < 8; ++j) {
    float c0j = (j == 0) ? -0.25f : ONE3;
    float c1j = (j <= 4) ? ONE3 : 0.0f;
    wc0[j] = (q16 == 0) ? c0j : ((q16 == 1) ? c1j : 0.0f);
    wc1[j] = (q16 == 2) ? c0j : ((q16 == 3) ? c1j : 0.0f);
  }
  float wm00 = (q16 == 0) ? -3.0f : wc0[0];
  float wm10 = (q16 == 2) ? -3.0f : wc1[0];
  bool mlt6 = (m16 < 6), m6 = (m16 == 6), m7 = (m16 == 7);
  union { bf16x8 v; unsigned w[4]; } am0, am1, bw;
  {
    float a0[8], a1[8];
#pragma unroll
    for (int j = 0; j < 8; ++j) {
      float wmj0 = (j == 0) ? wm00 : wc0[j];
      float wmj1 = (j == 0) ? wm10 : wc1[j];
      float alt0 = m6 ? wc0[j] : (m7 ? wmj0 : 0.0f);
      float alt1 = m6 ? wc1[j] : (m7 ? wmj1 : 0.0f);
      a0[j] = mlt6 ? wc0[j] * dxv[j] : alt0;
      a1[j] = mlt6 ? wc1[j] * dxv[j] : alt1;
    }
#pragma unroll
    for (int pr = 0; pr < 4; ++pr) {
      am0.w[pr] = pk2(a0[2*pr], a0[2*pr+1]);
      am1.w[pr] = pk2(a1[2*pr], a1[2*pr+1]);
      bw.w[pr]  = pk2(dxv[2*pr], dxv[2*pr+1]);
    }
  }
  f32x4 zz = {0.0f, 0.0f, 0.0f, 0.0f};
  f32x4 Dm0 = __builtin_amdgcn_mfma_f32_16x16x32_bf16(am0.v, bw.v, zz, 0, 0, 0);
  f32x4 Dm1 = __builtin_amdgcn_mfma_f32_16x16x32_bf16(am1.v, bw.v, zz, 0, 0, 0);

  // ---- stash U/cb/db (rows 0-7, cols 0-7) then uniform-broadcast read per half ----
  if (q16 < 2 && m16 < 8) {
#pragma unroll
    for (int i = 0; i < 4; ++i) {
      dxs[544 +      (4 * q16 + i) * 8 + m16] = Dm0[i];
      dxs[544 + 64 + (4 * q16 + i) * 8 + m16] = Dm1[i];
    }
  }
  const float* Ue = dxs + 544 + u * 64;
  float U[21], cbv[6], dbv[6];
#pragma unroll
  for (int i = 0; i < 6; ++i)
#pragma unroll
    for (int j = 0; j <= i; ++j) U[TRI(i,j)] = Ue[i * 8 + j];
#pragma unroll
  for (int j = 0; j < 6; ++j) { cbv[j] = Ue[48 + j]; dbv[j] = Ue[56 + j]; }

  // ---- uniform Q, R from ws ----
  const float* qro = (const float*)(ws + QOFF);
  float Qm[21], Rm[6];
#pragma unroll
  for (int t = 0; t < 21; ++t) Qm[t] = qro[t];
#pragma unroll
  for (int t = 0; t < 6; ++t) Rm[t] = qro[21 + t];

  // ---- epilogue (per half-wave batch, lanes redundant within half) ----
  float xp[6];
#pragma unroll
  for (int i = 0; i < 6; ++i) xp[i] = x0e[i] + dbv[i];
  float D[21];
#pragma unroll
  for (int i = 0; i < 6; ++i)
#pragma unroll
    for (int j = 0; j <= i; ++j) {
      float v = U[TRI(i,j)];
      v -= cbv[i] * dbv[j];
      v -= dbv[i] * cbv[j];
      v = fmaf(3.75f * dbv[i], dbv[j], v);   // sum(Wc) = 3.75
      D[TRI(i,j)] = v;
    }
  float s00 = D[TRI(0,0)] + Rm[TRI(0,0)];
  float s10 = D[TRI(1,0)] + Rm[TRI(1,0)];
  float s11 = D[TRI(1,1)] + Rm[TRI(1,1)];
  float s20 = D[TRI(2,0)] + Rm[TRI(2,0)];
  float s21 = D[TRI(2,1)] + Rm[TRI(2,1)];
  float s22 = D[TRI(2,2)] + Rm[TRI(2,2)];
  float a00 = s00 + 1e-5f, a11 = s11 + 1e-5f, a22 = s22 + 1e-5f;
  float a10 = s10, a20 = s20, a21 = s21;
  float adj00 = a11*a22 - a21*a21;
  float adj01 = a20*a21 - a10*a22;
  float adj02 = a10*a21 - a11*a20;
  float adj11 = a00*a22 - a20*a20;
  float adj12 = a10*a20 - a00*a21;
  float adj22 = a00*a11 - a10*a10;
  float det  = a00*adj00 + a10*adj01 + a20*adj02;
  float idet = 1.0f / det;
  float I00 = adj00*idet, I01 = adj01*idet, I02 = adj02*idet;
  float I11 = adj11*idet, I12 = adj12*idet, I22 = adj22*idet;

#define DS(i,j) ((i) >= (j) ? D[TRI(i,j)] : D[TRI(j,i)])
  float K_[18];
#pragma unroll
  for (int i = 0; i < 6; ++i) {
    float c0 = DS(i,0), c1 = DS(i,1), c2 = DS(i,2);
    K_[i*3+0] = c0*I00 + c1*I01 + c2*I02;
    K_[i*3+1] = c0*I01 + c1*I11 + c2*I12;
    K_[i*3+2] = c0*I02 + c1*I12 + c2*I22;
  }
  float inn0 = yy0 - xp[0], inn1 = yy1 - xp[1], inn2 = yy2 - xp[2];
  float xu[6];
#pragma unroll
  for (int i = 0; i < 6; ++i)
    xu[i] = xp[i] + K_[i*3]*inn0 + K_[i*3+1]*inn1 + K_[i*3+2]*inn2;

  float KS[18];
#pragma unroll
  for (int i = 0; i < 6; ++i) {
    float k0 = K_[i*3], k1 = K_[i*3+1], k2 = K_[i*3+2];
    KS[i*3+0] = k0*s00 + k1*s10 + k2*s20;
    KS[i*3+1] = k0*s10 + k1*s11 + k2*s21;
    KS[i*3+2] = k0*s20 + k1*s21 + k2*s22;
  }
  float Pu[21];
#pragma unroll
  for (int i = 0; i < 6; ++i)
#pragma unroll
    for (int j = 0; j <= i; ++j) {
      float v = D[TRI(i,j)] + Qm[TRI(i,j)];
      v -= KS[i*3]*K_[j*3] + KS[i*3+1]*K_[j*3+1] + KS[i*3+2]*K_[j*3+2];
      Pu[TRI(i,j)] = v + ((i==j) ? 1e-4f : 0.0f);
    }

  // ---- stores: lane 0 -> batch 2p, lane 32 -> batch 2p+1 ----
  if ((lane & 31) == 0) {
    int b = be;
    float* o_xu = out;
    float* o_Pu = out + (size_t)6  * B;
    float* o_xp = out + (size_t)42 * B;
    float* o_Pp = out + (size_t)48 * B;
    float* o_yp = out + (size_t)84 * B;
    float* o_S  = out + (size_t)87 * B;
    float* o_K  = out + (size_t)96 * B;
    {
      float* pp = o_xu + b * 6;
      ((float2*)pp)[0] = make_float2(xu[0], xu[1]);
      ((float2*)pp)[1] = make_float2(xu[2], xu[3]);
      ((float2*)pp)[2] = make_float2(xu[4], xu[5]);
    }
    {
      float* pp = o_Pu + b * 36;
#pragma unroll
      for (int i = 0; i < 6; ++i)
#pragma unroll
        for (int j = 0; j < 6; j += 2) {
          float v0 = (i>=j)   ? Pu[TRI(i,j)]   : Pu[TRI(j,i)];
          float v1 = (i>=j+1) ? Pu[TRI(i,j+1)] : Pu[TRI(j+1,i)];
          *(float2*)(pp + i*6 + j) = make_float2(v0, v1);
        }
    }
    {
      float* pp = o_xp + b * 6;
      ((float2*)pp)[0] = make_float2(xp[0], xp[1]);
      ((float2*)pp)[1] = make_float2(xp[2], xp[3]);
      ((float2*)pp)[2] = make_float2(xp[4], xp[5]);
    }
    {
      float* pp = o_Pp + b * 36;
#pragma unroll
      for (int i = 0; i < 6; ++i)
#pragma unroll
        for (int j = 0; j < 6; j += 2) {
          float v0 = ((i>=j)   ? D[TRI(i,j)]   : D[TRI(j,i)])   + ((i>=j)   ? Qm[TRI(i,j)]   : Qm[TRI(j,i)]);
          float v1 = ((i>=j+1) ? D[TRI(i,j+1)] : D[TRI(j+1,i)]) + ((i>=j+1) ? Qm[TRI(i,j+1)] : Qm[TRI(j+1,i)]);
          *(float2*)(pp + i*6 + j) = make_float2(v0, v1);
        }
    }
    {
      float* pp = o_yp + b * 3;
      pp[0] = xp[0]; pp[1] = xp[1]; pp[2] = xp[2];
    }
    {
      float* pp = o_S + b * 9;
      pp[0]=s00; pp[1]=s10; pp[2]=s20;
      pp[3]=s10; pp[4]=s11; pp[5]=s21;
      pp[6]=s20; pp[7]=s21; pp[8]=s22;
    }
    {
      float* pp = o_K + b * 18;
#pragma unroll
      for (int i = 0; i < 9; ++i)
        ((float2*)pp)[i] = make_float2(K_[i*2], K_[i*2+1]);
    }
  }
}

extern "C" void kernel_launch(void* const* d_in, const int* in_sizes, int n_in,
                              void* d_out, int out_size, void* d_ws, size_t ws_size,
                              hipStream_t stream) {
  const float* x  = (const float*)d_in[0];
  const float* P  = (const float*)d_in[1];
  const float* u  = (const float*)d_in[2];
  const float* y  = (const float*)d_in[3];
  const float* LQ = (const float*)d_in[4];
  const float* LR = (const float*)d_in[5];
  const float* W1 = (const float*)d_in[6];
  const float* b1 = (const float*)d_in[7];
  const float* W2 = (const float*)d_in[8];
  const float* b2 = (const float*)d_in[9];
  float* out = (float*)d_out;
  char*  ws  = (char*)d_ws;
  int B = in_sizes[0] / 6;

  hipLaunchKernelGGL(pack_frags, dim3(1), dim3(64), 0, stream, W1, b1, W2, LQ, LR, ws);
  int blocks = (B + 7) / 8;   // 4 waves/block, 2 batches/wave
  hipLaunchKernelGGL(ukf_mfma2, dim3(blocks), dim3(256), 0, stream,
                     x, P, u, y, b2, (const char*)ws, out, B);
}

// Round 5
// 240.695 us; speedup vs baseline: 1.9065x; 1.1979x over previous
//
#include <hip/hip_runtime.h>
#include <math.h>

typedef __attribute__((ext_vector_type(8)))  short bf16x8;
typedef __attribute__((ext_vector_type(4)))  float f32x4;
typedef __attribute__((ext_vector_type(16))) float f32x16;
typedef __attribute__((ext_vector_type(2)))  float f32x2;

#define TRI(i,j) (((i)*((i)+1))/2 + (j))
#define ONE3 0.3333333333333333f
#define QOFF 6144   /* Q/R consts after 64*96B frag records */
#define LOFF 8192   /* cholesky L buffer: [batch][40] f32 (cols 0..5 x 6 rows, col-major) */

// RNE f32->bf16 (moment fragments: precision matters)
static __device__ __forceinline__ unsigned short f2b(float f) {
  union { float f; unsigned u; } v; v.f = f;
  unsigned r = v.u + 0x7FFFu + ((v.u >> 16) & 1u);
  return (unsigned short)(r >> 16);
}
static __device__ __forceinline__ unsigned pk2(float lo, float hi) {
  return (unsigned)f2b(lo) | ((unsigned)f2b(hi) << 16);
}
// truncating pack (NN path, dt-damped)
static __device__ __forceinline__ unsigned pk2t(float lo, float hi) {
  return __builtin_amdgcn_perm(__float_as_uint(hi), __float_as_uint(lo), 0x07060302u);
}

// odd deg-7 tanh approx, fitted [-3,3]; NO clamp: |z| <= ~3 by construction
// (W1 col norms ~0.3, |state| <~ 6; rare overflow damped by dt/6*W2 -> <1e-2 on outputs)
#define TC0 0.970866f
#define TC1 (-0.217815f)
#define TC2 0.028904f
#define TC3 (-0.0014079f)

static __device__ __forceinline__ unsigned tanh2_pk(float a, float b) {
#if __has_builtin(__builtin_elementwise_fma)
  f32x2 z; z[0] = a; z[1] = b;
  f32x2 k3 = {TC3, TC3}, k2 = {TC2, TC2}, k1 = {TC1, TC1}, k0 = {TC0, TC0};
  f32x2 t = z * z;
  f32x2 p = __builtin_elementwise_fma(t, k3, k2);
  p = __builtin_elementwise_fma(p, t, k1);
  p = __builtin_elementwise_fma(p, t, k0);
  f32x2 r = z * p;
  return pk2t(r[0], r[1]);
#else
  float ta = a * a, tb = b * b;
  float pa = fmaf(fmaf(fmaf(TC3, ta, TC2), ta, TC1), ta, TC0);
  float pb = fmaf(fmaf(fmaf(TC3, tb, TC2), tb, TC1), tb, TC0);
  return pk2t(a * pa, b * pb);
#endif
}

// ---- setup: per-lane 32x32x16 weight fragments (96B/lane) + Q/R consts ----
__global__ void pack_frags(const float* __restrict__ W1, const float* __restrict__ b1,
                           const float* __restrict__ W2,
                           const float* __restrict__ LQ, const float* __restrict__ LR,
                           char* __restrict__ ws) {
  int lane = threadIdx.x;          // 0..63
  int mr = lane & 31, u = lane >> 5;
  unsigned* A1 = (unsigned*)(ws + lane * 96);
  unsigned* A2 = (unsigned*)(ws + lane * 96 + 32);
#pragma unroll
  for (int t = 0; t < 2; ++t) {
    int h = 32 * t + mr;
    if (u == 0) {
#pragma unroll
      for (int p = 0; p < 4; ++p)
        A1[t * 4 + p] = pk2(W1[(2 * p) * 64 + h], W1[(2 * p + 1) * 64 + h]);
    } else {
      A1[t * 4 + 0] = pk2(b1[h], 0.0f);
      A1[t * 4 + 1] = 0u; A1[t * 4 + 2] = 0u; A1[t * 4 + 3] = 0u;
    }
  }
#pragma unroll
  for (int kq = 0; kq < 4; ++kq) {
#pragma unroll
    for (int p = 0; p < 4; ++p) {
      float lo = (mr < 6) ? W2[(16 * kq + 8 * u + 2 * p) * 6 + mr] : 0.0f;
      float hi = (mr < 6) ? W2[(16 * kq + 8 * u + 2 * p + 1) * 6 + mr] : 0.0f;
      A2[kq * 4 + p] = pk2(lo, hi);
    }
  }
  if (lane == 0) {
    float* qo = (float*)(ws + QOFF);
    for (int i = 0; i < 6; ++i)
      for (int j = 0; j <= i; ++j) {
        float s = (i == j) ? 1e-7f : 0.0f;
        for (int k = 0; k <= j; ++k) s = fmaf(LQ[i * 6 + k], LQ[j * 6 + k], s);
        qo[TRI(i, j)] = s;
      }
    for (int i = 0; i < 3; ++i)
      for (int j = 0; j <= i; ++j) {
        float s = (i == j) ? 1e-7f : 0.0f;
        for (int k = 0; k <= j; ++k) s = fmaf(LR[i * 3 + k], LR[j * 3 + k], s);
        qo[21 + TRI(i, j)] = s;
      }
  }
}

// ---- prep: 1 thread/batch cholesky -> Lbuf[batch][40] (col-major, zeros above diag) ----
__global__ void prep_chol(const float* __restrict__ gP, float* __restrict__ Lbuf, int B) {
  int b = blockIdx.x * blockDim.x + threadIdx.x;
  if (b >= B) return;
  float Pf[36];
  const float4* p4 = (const float4*)(gP + (size_t)b * 36);
#pragma unroll
  for (int q = 0; q < 9; ++q) {
    float4 v = p4[q];
    Pf[q*4+0]=v.x; Pf[q*4+1]=v.y; Pf[q*4+2]=v.z; Pf[q*4+3]=v.w;
  }
  float base[21], Lt[21];
#pragma unroll
  for (int i = 0; i < 6; ++i)
#pragma unroll
    for (int j = 0; j <= i; ++j)
      base[TRI(i,j)] = 0.75f * (Pf[i*6+j] + Pf[j*6+i]) + ((i==j) ? 1e-5f : 0.0f);
#pragma unroll
  for (int k = 0; k < 6; ++k) {
    float s = base[TRI(k,k)];
#pragma unroll
    for (int m2 = 0; m2 < k; ++m2) s = fmaf(-Lt[TRI(k,m2)], Lt[TRI(k,m2)], s);
    float d = sqrtf(s);
    Lt[TRI(k,k)] = d;
    float inv = 1.0f / d;
#pragma unroll
    for (int i = k + 1; i < 6; ++i) {
      float s2 = base[TRI(i,k)];
#pragma unroll
      for (int m2 = 0; m2 < k; ++m2) s2 = fmaf(-Lt[TRI(i,m2)], Lt[TRI(k,m2)], s2);
      Lt[TRI(i,k)] = s2 * inv;
    }
  }
  float* lp = Lbuf + (size_t)b * 40;
#pragma unroll
  for (int c = 0; c < 6; ++c)
#pragma unroll
    for (int f = 0; f < 6; ++f)
      lp[c * 6 + f] = (f >= c) ? Lt[TRI(f, c)] : 0.0f;
}

// ---- main: one wave = 2 batches; RK4 via 32x32x16 MFMA; moments -> Ubuf[batch][48] ----
__launch_bounds__(256, 4)
__global__ void ukf_main(const float* __restrict__ gx,
                         const float* __restrict__ gu,
                         const float* __restrict__ gb2,
                         const float* __restrict__ Lbuf,
                         const char*  __restrict__ ws,
                         float* __restrict__ Ubuf, int B) {
  __shared__ f32x4 ldsv[4][136];   // per wave: dx[32 cols][17] f32
  int lane = threadIdx.x & 63;
  int wid  = threadIdx.x >> 6;
  int p    = blockIdx.x * 4 + wid;           // batch pair
  if (2 * p >= B) return;
  int u   = lane >> 5;
  int c   = lane & 31;
  int q16 = lane >> 4, m16 = lane & 15;
  int bc  = 2 * p + ((lane >> 4) & 1);       // this column's batch
  float* dxs = (float*)&ldsv[wid][0];

  // sigma column ids + L column load (issue early)
  int   sidx = c & 15;
  float sgn = (sidx == 0 || sidx > 12) ? 0.0f : ((sidx <= 6) ? 1.0f : -1.0f);
  int   cc  = (sidx >= 1 && sidx <= 6) ? (sidx - 1) : ((sidx >= 7) ? (sidx - 7) : 0);
  const float* lp = Lbuf + (size_t)bc * 40 + cc * 6;
  float Lc[6];
#pragma unroll
  for (int f = 0; f < 6; ++f) Lc[f] = lp[f];

  float x0c[6];
  {
    const float* xb = gx + (size_t)bc * 6;
    float2 t0 = *(const float2*)(xb);
    float2 t1 = *(const float2*)(xb + 2);
    float2 t2 = *(const float2*)(xb + 4);
    x0c[0]=t0.x; x0c[1]=t0.y; x0c[2]=t1.x; x0c[3]=t1.y; x0c[4]=t2.x; x0c[5]=t2.y;
  }
  float2 uu = *(const float2*)(gu + (size_t)bc * 2);
  unsigned uu_pk = pk2(uu.x, uu.y);

  // weight fragments
  const char* wp = ws + lane * 96;
  bf16x8 A1v0 = *((const bf16x8*)wp);
  bf16x8 A1v1 = *((const bf16x8*)(wp + 16));
  bf16x8 A2v[4];
#pragma unroll
  for (int kq = 0; kq < 4; ++kq) A2v[kq] = *((const bf16x8*)(wp + 32 + kq * 16));
  float b2r[6];
#pragma unroll
  for (int i = 0; i < 6; ++i) b2r[i] = gb2[i];

  float sgnL[6], xs[6];
#pragma unroll
  for (int f = 0; f < 6; ++f) { sgnL[f] = sgn * Lc[f]; xs[f] = x0c[f] + sgnL[f]; }

  // ---- RK4 ----
  float kf[6]   = {0,0,0,0,0,0};
  float ksum[6] = {0,0,0,0,0,0};
  f32x16 z16;
#pragma unroll
  for (int i = 0; i < 16; ++i) z16[i] = 0.0f;
#pragma unroll
  for (int st = 0; st < 4; ++st) {
    const float cin = (st == 3) ? 0.01f : 0.005f;
    float xi[6];
#pragma unroll
    for (int f = 0; f < 6; ++f) xi[f] = fmaf(cin, kf[f], xs[f]);
    // layer1 B: u=1 lanes only need k=8 slot == 1.0 (A rows k=9..15 are zero)
    union { bf16x8 v; unsigned w[4]; } bx;
    bx.w[0] = u ? 0x00003F80u : pk2t(xi[0], xi[1]);
    bx.w[1] = pk2t(xi[2], xi[3]);
    bx.w[2] = pk2t(xi[4], xi[5]);
    bx.w[3] = uu_pk;
    f32x16 d1a = __builtin_amdgcn_mfma_f32_32x32x16_bf16(A1v0, bx.v, z16, 0, 0, 0);
    f32x16 d1b = __builtin_amdgcn_mfma_f32_32x32x16_bf16(A1v1, bx.v, z16, 0, 0, 0);
    unsigned Hpk[16];
#pragma unroll
    for (int pr = 0; pr < 8; ++pr) Hpk[pr]     = tanh2_pk(d1a[2*pr], d1a[2*pr+1]);
#pragma unroll
    for (int pr = 0; pr < 8; ++pr) Hpk[8 + pr] = tanh2_pk(d1b[2*pr], d1b[2*pr+1]);
    // layer2: B-frag rows via partner exchange (xor 32)
    f32x16 d2 = z16;
#pragma unroll
    for (int kq = 0; kq < 4; ++kq) {
      int base = 8 * (kq >> 1) + 4 * (kq & 1);
      unsigned vA = u ? Hpk[base + 0] : Hpk[base + 2];
      unsigned vB = u ? Hpk[base + 1] : Hpk[base + 3];
      unsigned rA = __shfl_xor(vA, 32, 64);
      unsigned rB = __shfl_xor(vB, 32, 64);
      union { bf16x8 v; unsigned w[4]; } bh;
      bh.w[0] = u ? rA : Hpk[base + 0];
      bh.w[1] = u ? rB : Hpk[base + 1];
      bh.w[2] = u ? Hpk[base + 2] : rA;
      bh.w[3] = u ? Hpk[base + 3] : rB;
      d2 = __builtin_amdgcn_mfma_f32_32x32x16_bf16(A2v[kq], bh.v, d2, 0, 0, 0);
    }
    float e0 = __shfl_xor(d2[0], 32, 64);
    float e1 = __shfl_xor(d2[1], 32, 64);
    float e2 = __shfl_xor(d2[2], 32, 64);
    float e3 = __shfl_xor(d2[3], 32, 64);
    kf[0] = (u ? e0 : d2[0]) + b2r[0];
    kf[1] = (u ? e1 : d2[1]) + b2r[1];
    kf[2] = (u ? e2 : d2[2]) + b2r[2];
    kf[3] = (u ? e3 : d2[3]) + b2r[3];
    kf[4] = (u ? d2[0] : e0) + b2r[4];
    kf[5] = (u ? d2[1] : e1) + b2r[5];
    const float wks = (st == 0 || st == 3) ? 1.0f : 2.0f;
#pragma unroll
    for (int f = 0; f < 6; ++f) ksum[f] = fmaf(wks, kf[f], ksum[f]);
  }

  // deltas -> LDS (stride 17, conflict-free); both halves identical, u==0 writes
  const float dt6 = 0.01f / 6.0f;
  if (u == 0) {
#pragma unroll
    for (int f = 0; f < 6; ++f) dxs[c * 17 + f] = fmaf(dt6, ksum[f], sgnL[f]);
  }

  // ---- moments: two 16x16x32 MFMAs, shared B = dx ----
  float dxv[8];
#pragma unroll
  for (int j = 0; j < 8; ++j) dxv[j] = dxs[(8 * q16 + j) * 17 + m16];
  float wc0[8], wc1[8];
#pragma unroll
  for (int j = 0; j < 8; ++j) {
    float c0j = (j == 0) ? -0.25f : ONE3;
    float c1j = (j <= 4) ? ONE3 : 0.0f;
    wc0[j] = (q16 == 0) ? c0j : ((q16 == 1) ? c1j : 0.0f);
    wc1[j] = (q16 == 2) ? c0j : ((q16 == 3) ? c1j : 0.0f);
  }
  float wm00 = (q16 == 0) ? -3.0f : wc0[0];
  float wm10 = (q16 == 2) ? -3.0f : wc1[0];
  bool mlt6 = (m16 < 6), m6 = (m16 == 6), m7 = (m16 == 7);
  union { bf16x8 v; unsigned w[4]; } am0, am1, bw;
  {
    float a0[8], a1[8];
#pragma unroll
    for (int j = 0; j < 8; ++j) {
      float wmj0 = (j == 0) ? wm00 : wc0[j];
      float wmj1 = (j == 0) ? wm10 : wc1[j];
      float alt0 = m6 ? wc0[j] : (m7 ? wmj0 : 0.0f);
      float alt1 = m6 ? wc1[j] : (m7 ? wmj1 : 0.0f);
      a0[j] = mlt6 ? wc0[j] * dxv[j] : alt0;
      a1[j] = mlt6 ? wc1[j] * dxv[j] : alt1;
    }
#pragma unroll
    for (int pr = 0; pr < 4; ++pr) {
      am0.w[pr] = pk2(a0[2*pr], a0[2*pr+1]);
      am1.w[pr] = pk2(a1[2*pr], a1[2*pr+1]);
      bw.w[pr]  = pk2(dxv[2*pr], dxv[2*pr+1]);
    }
  }
  f32x4 zz = {0.0f, 0.0f, 0.0f, 0.0f};
  f32x4 Dm0 = __builtin_amdgcn_mfma_f32_16x16x32_bf16(am0.v, bw.v, zz, 0, 0, 0);
  f32x4 Dm1 = __builtin_amdgcn_mfma_f32_16x16x32_bf16(am1.v, bw.v, zz, 0, 0, 0);

  // ---- store U/cb/db rows 0..7 x cols 0..5 -> Ubuf[batch][48] ----
  if (q16 < 2 && m16 < 6) {
    float* u0 = Ubuf + (size_t)(2 * p) * 48;
    float* u1 = Ubuf + (size_t)(2 * p + 1) * 48;
#pragma unroll
    for (int i = 0; i < 4; ++i) {
      u0[(4 * q16 + i) * 6 + m16] = Dm0[i];
      u1[(4 * q16 + i) * 6 + m16] = Dm1[i];
    }
  }
}

// ---- epilogue: 1 thread/batch; D,S,inv,K,xu,Pu + all output stores ----
__global__ void ukf_epi(const float* __restrict__ gx,
                        const float* __restrict__ gy,
                        const char*  __restrict__ ws,
                        const float* __restrict__ Ubuf,
                        float* __restrict__ out, int B) {
  int b = blockIdx.x * blockDim.x + threadIdx.x;
  if (b >= B) return;
  const float* rec = Ubuf + (size_t)b * 48;
  float U[21], cbv[6], dbv[6];
#pragma unroll
  for (int i = 0; i < 6; ++i)
#pragma unroll
    for (int j = 0; j <= i; ++j) U[TRI(i,j)] = rec[i * 6 + j];
#pragma unroll
  for (int j = 0; j < 6; ++j) { cbv[j] = rec[36 + j]; dbv[j] = rec[42 + j]; }

  float x0[6];
  {
    const float* xb = gx + (size_t)b * 6;
    float2 t0 = *(const float2*)(xb);
    float2 t1 = *(const float2*)(xb + 2);
    float2 t2 = *(const float2*)(xb + 4);
    x0[0]=t0.x; x0[1]=t0.y; x0[2]=t1.x; x0[3]=t1.y; x0[4]=t2.x; x0[5]=t2.y;
  }
  const float* yb = gy + (size_t)b * 3;
  float yy0 = yb[0], yy1 = yb[1], yy2 = yb[2];

  const float* qro = (const float*)(ws + QOFF);   // wave-uniform -> scalar loads
  float Qm[21], Rm[6];
#pragma unroll
  for (int t = 0; t < 21; ++t) Qm[t] = qro[t];
#pragma unroll
  for (int t = 0; t < 6; ++t) Rm[t] = qro[21 + t];

  float xp[6];
#pragma unroll
  for (int i = 0; i < 6; ++i) xp[i] = x0[i] + dbv[i];
  float D[21];
#pragma unroll
  for (int i = 0; i < 6; ++i)
#pragma unroll
    for (int j = 0; j <= i; ++j) {
      float v = U[TRI(i,j)];
      v -= cbv[i] * dbv[j];
      v -= dbv[i] * cbv[j];
      v = fmaf(3.75f * dbv[i], dbv[j], v);   // sum(Wc) = 3.75
      D[TRI(i,j)] = v;
    }
  float s00 = D[TRI(0,0)] + Rm[TRI(0,0)];
  float s10 = D[TRI(1,0)] + Rm[TRI(1,0)];
  float s11 = D[TRI(1,1)] + Rm[TRI(1,1)];
  float s20 = D[TRI(2,0)] + Rm[TRI(2,0)];
  float s21 = D[TRI(2,1)] + Rm[TRI(2,1)];
  float s22 = D[TRI(2,2)] + Rm[TRI(2,2)];
  float a00 = s00 + 1e-5f, a11 = s11 + 1e-5f, a22 = s22 + 1e-5f;
  float a10 = s10, a20 = s20, a21 = s21;
  float adj00 = a11*a22 - a21*a21;
  float adj01 = a20*a21 - a10*a22;
  float adj02 = a10*a21 - a11*a20;
  float adj11 = a00*a22 - a20*a20;
  float adj12 = a10*a20 - a00*a21;
  float adj22 = a00*a11 - a10*a10;
  float det  = a00*adj00 + a10*adj01 + a20*adj02;
  float idet = 1.0f / det;
  float I00 = adj00*idet, I01 = adj01*idet, I02 = adj02*idet;
  float I11 = adj11*idet, I12 = adj12*idet, I22 = adj22*idet;

#define DS(i,j) ((i) >= (j) ? D[TRI(i,j)] : D[TRI(j,i)])
  float K_[18];
#pragma unroll
  for (int i = 0; i < 6; ++i) {
    float c0 = DS(i,0), c1 = DS(i,1), c2 = DS(i,2);
    K_[i*3+0] = c0*I00 + c1*I01 + c2*I02;
    K_[i*3+1] = c0*I01 + c1*I11 + c2*I12;
    K_[i*3+2] = c0*I02 + c1*I12 + c2*I22;
  }
  float inn0 = yy0 - xp[0], inn1 = yy1 - xp[1], inn2 = yy2 - xp[2];
  float xu[6];
#pragma unroll
  for (int i = 0; i < 6; ++i)
    xu[i] = xp[i] + K_[i*3]*inn0 + K_[i*3+1]*inn1 + K_[i*3+2]*inn2;

  float KS[18];
#pragma unroll
  for (int i = 0; i < 6; ++i) {
    float k0 = K_[i*3], k1 = K_[i*3+1], k2 = K_[i*3+2];
    KS[i*3+0] = k0*s00 + k1*s10 + k2*s20;
    KS[i*3+1] = k0*s10 + k1*s11 + k2*s21;
    KS[i*3+2] = k0*s20 + k1*s21 + k2*s22;
  }
  float Pu[21];
#pragma unroll
  for (int i = 0; i < 6; ++i)
#pragma unroll
    for (int j = 0; j <= i; ++j) {
      float v = D[TRI(i,j)] + Qm[TRI(i,j)];
      v -= KS[i*3]*K_[j*3] + KS[i*3+1]*K_[j*3+1] + KS[i*3+2]*K_[j*3+2];
      Pu[TRI(i,j)] = v + ((i==j) ? 1e-4f : 0.0f);
    }

  float* o_xu = out;
  float* o_Pu = out + (size_t)6  * B;
  float* o_xp = out + (size_t)42 * B;
  float* o_Pp = out + (size_t)48 * B;
  float* o_yp = out + (size_t)84 * B;
  float* o_S  = out + (size_t)87 * B;
  float* o_K  = out + (size_t)96 * B;
  {
    float* pp = o_xu + (size_t)b * 6;
    ((float2*)pp)[0] = make_float2(xu[0], xu[1]);
    ((float2*)pp)[1] = make_float2(xu[2], xu[3]);
    ((float2*)pp)[2] = make_float2(xu[4], xu[5]);
  }
  {
    float* pp = o_Pu + (size_t)b * 36;
#pragma unroll
    for (int i = 0; i < 6; ++i)
#pragma unroll
      for (int j = 0; j < 6; j += 2) {
        float v0 = (i>=j)   ? Pu[TRI(i,j)]   : Pu[TRI(j,i)];
        float v1 = (i>=j+1) ? Pu[TRI(i,j+1)] : Pu[TRI(j+1,i)];
        *(float2*)(pp + i*6 + j) = make_float2(v0, v1);
      }
  }
  {
    float* pp = o_xp + (size_t)b * 6;
    ((float2*)pp)[0] = make_float2(xp[0], xp[1]);
    ((float2*)pp)[1] = make_float2(xp[2], xp[3]);
    ((float2*)pp)[2] = make_float2(xp[4], xp[5]);
  }
  {
    float* pp = o_Pp + (size_t)b * 36;
#pragma unroll
    for (int i = 0; i < 6; ++i)
#pragma unroll
      for (int j = 0; j < 6; j += 2) {
        float v0 = ((i>=j)   ? D[TRI(i,j)]   : D[TRI(j,i)])   + ((i>=j)   ? Qm[TRI(i,j)]   : Qm[TRI(j,i)]);
        float v1 = ((i>=j+1) ? D[TRI(i,j+1)] : D[TRI(j+1,i)]) + ((i>=j+1) ? Qm[TRI(i,j+1)] : Qm[TRI(j+1,i)]);
        *(float2*)(pp + i*6 + j) = make_float2(v0, v1);
      }
  }
  {
    float* pp = o_yp + (size_t)b * 3;
    pp[0] = xp[0]; pp[1] = xp[1]; pp[2] = xp[2];
  }
  {
    float* pp = o_S + (size_t)b * 9;
    pp[0]=s00; pp[1]=s10; pp[2]=s20;
    pp[3]=s10; pp[4]=s11; pp[5]=s21;
    pp[6]=s20; pp[7]=s21; pp[8]=s22;
  }
  {
    float* pp = o_K + (size_t)b * 18;
#pragma unroll
    for (int i = 0; i < 9; ++i)
      ((float2*)pp)[i] = make_float2(K_[i*2], K_[i*2+1]);
  }
}

extern "C" void kernel_launch(void* const* d_in, const int* in_sizes, int n_in,
                              void* d_out, int out_size, void* d_ws, size_t ws_size,
                              hipStream_t stream) {
  const float* x  = (const float*)d_in[0];
  const float* P  = (const float*)d_in[1];
  const float* u  = (const float*)d_in[2];
  const float* y  = (const float*)d_in[3];
  const float* LQ = (const float*)d_in[4];
  const float* LR = (const float*)d_in[5];
  const float* W1 = (const float*)d_in[6];
  const float* b1 = (const float*)d_in[7];
  const float* W2 = (const float*)d_in[8];
  const float* b2 = (const float*)d_in[9];
  float* out = (float*)d_out;
  char*  ws  = (char*)d_ws;
  int B = in_sizes[0] / 6;

  // ws layout: [0,6144) frags | [6144,6144+108) Q/R | [8192, +B*160) Lbuf | then Ubuf B*192
  float* Lbuf = (float*)(ws + LOFF);
  float* Ubuf = (float*)(ws + LOFF + (size_t)B * 160);

  hipLaunchKernelGGL(pack_frags, dim3(1), dim3(64), 0, stream, W1, b1, W2, LQ, LR, ws);
  hipLaunchKernelGGL(prep_chol, dim3((B + 255) / 256), dim3(256), 0, stream, P, Lbuf, B);
  hipLaunchKernelGGL(ukf_main, dim3((B + 7) / 8), dim3(256), 0, stream,
                     x, u, b2, (const float*)Lbuf, (const char*)ws, Ubuf, B);
  hipLaunchKernelGGL(ukf_epi, dim3((B + 255) / 256), dim3(256), 0, stream,
                     x, y, (const char*)ws, (const float*)Ubuf, out, B);
}

// Round 6
// 234.327 us; speedup vs baseline: 1.9583x; 1.0272x over previous
//
#include <hip/hip_runtime.h>
#include <math.h>

typedef __attribute__((ext_vector_type(8)))  short bf16x8;
typedef __attribute__((ext_vector_type(4)))  float f32x4;
typedef __attribute__((ext_vector_type(16))) float f32x16;
typedef __attribute__((ext_vector_type(2)))  float f32x2;

#define TRI(i,j) (((i)*((i)+1))/2 + (j))
#define ONE3 0.3333333333333333f
#define QOFF 6144   /* Q/R consts after 64*96B frag records */
#define LOFF 8192   /* cholesky L buffer: [batch][40] f32 */

// RNE f32->bf16 (moment fragments: precision matters)
static __device__ __forceinline__ unsigned short f2b(float f) {
  union { float f; unsigned u; } v; v.f = f;
  unsigned r = v.u + 0x7FFFu + ((v.u >> 16) & 1u);
  return (unsigned short)(r >> 16);
}
static __device__ __forceinline__ unsigned pk2(float lo, float hi) {
  return (unsigned)f2b(lo) | ((unsigned)f2b(hi) << 16);
}
// truncating pack (NN path, dt-damped)
static __device__ __forceinline__ unsigned pk2t(float lo, float hi) {
  return __builtin_amdgcn_perm(__float_as_uint(hi), __float_as_uint(lo), 0x07060302u);
}

// odd deg-7 tanh approx, fitted [-3,3]; no clamp (preactivations bounded, dt-damped)
#define TC0 0.970866f
#define TC1 (-0.217815f)
#define TC2 0.028904f
#define TC3 (-0.0014079f)

static __device__ __forceinline__ unsigned tanh2_pk(float a, float b) {
#if __has_builtin(__builtin_elementwise_fma)
  f32x2 z; z[0] = a; z[1] = b;
  f32x2 k3 = {TC3, TC3}, k2 = {TC2, TC2}, k1 = {TC1, TC1}, k0 = {TC0, TC0};
  f32x2 t = z * z;
  f32x2 p = __builtin_elementwise_fma(t, k3, k2);
  p = __builtin_elementwise_fma(p, t, k1);
  p = __builtin_elementwise_fma(p, t, k0);
  f32x2 r = z * p;
  return pk2t(r[0], r[1]);
#else
  float ta = a * a, tb = b * b;
  float pa = fmaf(fmaf(fmaf(TC3, ta, TC2), ta, TC1), ta, TC0);
  float pb = fmaf(fmaf(fmaf(TC3, tb, TC2), tb, TC1), tb, TC0);
  return pk2t(a * pa, b * pb);
#endif
}

// ---- prep: per-batch cholesky -> Lbuf; block 0 lanes 0..63 also pack weight frags ----
// A2 k-slot permutation: hidden(kq,u,j) = 32*(kq>>1) + 16*(kq&1) + 4u + (j<4?j:j+4)
// so each lane's D1 C-layout regs Hpk[4kq..4kq+3] ARE the layer-2 B fragment (no exchange).
__global__ void prep_kernel(const float* __restrict__ gP,
                            const float* __restrict__ W1, const float* __restrict__ b1,
                            const float* __restrict__ W2,
                            const float* __restrict__ LQ, const float* __restrict__ LR,
                            char* __restrict__ ws, float* __restrict__ Lbuf, int B) {
  if (blockIdx.x == 0 && threadIdx.x < 64) {
    int lane = threadIdx.x;
    int mr = lane & 31, u = lane >> 5;
    unsigned* A1 = (unsigned*)(ws + lane * 96);
    unsigned* A2 = (unsigned*)(ws + lane * 96 + 32);
#pragma unroll
    for (int t = 0; t < 2; ++t) {
      int h = 32 * t + mr;
      if (u == 0) {
#pragma unroll
        for (int p = 0; p < 4; ++p)
          A1[t * 4 + p] = pk2(W1[(2 * p) * 64 + h], W1[(2 * p + 1) * 64 + h]);
      } else {
        A1[t * 4 + 0] = pk2(b1[h], 0.0f);
        A1[t * 4 + 1] = 0u; A1[t * 4 + 2] = 0u; A1[t * 4 + 3] = 0u;
      }
    }
#pragma unroll
    for (int kq = 0; kq < 4; ++kq) {
#pragma unroll
      for (int p = 0; p < 4; ++p) {
        int rm = 2 * p + ((p >= 2) ? 4 : 0);
        int hid = 32 * (kq >> 1) + 16 * (kq & 1) + 4 * u + rm;
        float lo = (mr < 6) ? W2[hid * 6 + mr] : 0.0f;
        float hi = (mr < 6) ? W2[(hid + 1) * 6 + mr] : 0.0f;
        A2[kq * 4 + p] = pk2(lo, hi);
      }
    }
    if (lane == 0) {
      float* qo = (float*)(ws + QOFF);
      for (int i = 0; i < 6; ++i)
        for (int j = 0; j <= i; ++j) {
          float s = (i == j) ? 1e-7f : 0.0f;
          for (int k = 0; k <= j; ++k) s = fmaf(LQ[i * 6 + k], LQ[j * 6 + k], s);
          qo[TRI(i, j)] = s;
        }
      for (int i = 0; i < 3; ++i)
        for (int j = 0; j <= i; ++j) {
          float s = (i == j) ? 1e-7f : 0.0f;
          for (int k = 0; k <= j; ++k) s = fmaf(LR[i * 3 + k], LR[j * 3 + k], s);
          qo[21 + TRI(i, j)] = s;
        }
    }
  }

  int b = blockIdx.x * blockDim.x + threadIdx.x;
  if (b >= B) return;
  float Pf[36];
  const float4* p4 = (const float4*)(gP + (size_t)b * 36);
#pragma unroll
  for (int q = 0; q < 9; ++q) {
    float4 v = p4[q];
    Pf[q*4+0]=v.x; Pf[q*4+1]=v.y; Pf[q*4+2]=v.z; Pf[q*4+3]=v.w;
  }
  float base[21], Lt[21];
#pragma unroll
  for (int i = 0; i < 6; ++i)
#pragma unroll
    for (int j = 0; j <= i; ++j)
      base[TRI(i,j)] = 0.75f * (Pf[i*6+j] + Pf[j*6+i]) + ((i==j) ? 1e-5f : 0.0f);
#pragma unroll
  for (int k = 0; k < 6; ++k) {
    float s = base[TRI(k,k)];
#pragma unroll
    for (int m2 = 0; m2 < k; ++m2) s = fmaf(-Lt[TRI(k,m2)], Lt[TRI(k,m2)], s);
    float d = sqrtf(s);
    Lt[TRI(k,k)] = d;
    float inv = 1.0f / d;
#pragma unroll
    for (int i = k + 1; i < 6; ++i) {
      float s2 = base[TRI(i,k)];
#pragma unroll
      for (int m2 = 0; m2 < k; ++m2) s2 = fmaf(-Lt[TRI(i,m2)], Lt[TRI(k,m2)], s2);
      Lt[TRI(i,k)] = s2 * inv;
    }
  }
  float* lp = Lbuf + (size_t)b * 40;
#pragma unroll
  for (int c = 0; c < 6; ++c)
#pragma unroll
    for (int f = 0; f < 6; ++f)
      lp[c * 6 + f] = (f >= c) ? Lt[TRI(f, c)] : 0.0f;
}

// ---- main: one wave = 2 batches; zero-exchange K-loop ----
__launch_bounds__(256, 4)
__global__ void ukf_main(const float* __restrict__ gx,
                         const float* __restrict__ gu,
                         const float* __restrict__ gb2,
                         const float* __restrict__ Lbuf,
                         const char*  __restrict__ ws,
                         float* __restrict__ Ubuf, int B) {
  __shared__ f32x4 ldsv[4][136];   // per wave: dx[32 cols][17] f32
  int lane = threadIdx.x & 63;
  int wid  = threadIdx.x >> 6;
  int p    = blockIdx.x * 4 + wid;
  if (2 * p >= B) return;
  int u   = lane >> 5;
  int c   = lane & 31;
  int q16 = lane >> 4, m16 = lane & 15;
  int bc  = 2 * p + ((lane >> 4) & 1);
  float* dxs = (float*)&ldsv[wid][0];

  // sigma column ids + L column load
  int   sidx = c & 15;
  float sgn = (sidx == 0 || sidx > 12) ? 0.0f : ((sidx <= 6) ? 1.0f : -1.0f);
  int   cc  = (sidx >= 1 && sidx <= 6) ? (sidx - 1) : ((sidx >= 7) ? (sidx - 7) : 0);
  if (cc > 5) cc = 5;
  const float* lpr = Lbuf + (size_t)bc * 40 + cc * 6;
  float Lc[6];
#pragma unroll
  for (int f = 0; f < 6; ++f) Lc[f] = lpr[f];

  float x0c[6];
  {
    const float* xb = gx + (size_t)bc * 6;
    float2 t0 = *(const float2*)(xb);
    float2 t1 = *(const float2*)(xb + 2);
    float2 t2 = *(const float2*)(xb + 4);
    x0c[0]=t0.x; x0c[1]=t0.y; x0c[2]=t1.x; x0c[3]=t1.y; x0c[4]=t2.x; x0c[5]=t2.y;
  }
  float2 uu = *(const float2*)(gu + (size_t)bc * 2);
  unsigned uu_pk = pk2(uu.x, uu.y);

  const char* wp = ws + lane * 96;
  bf16x8 A1v0 = *((const bf16x8*)wp);
  bf16x8 A1v1 = *((const bf16x8*)(wp + 16));
  bf16x8 A2v[4];
#pragma unroll
  for (int kq = 0; kq < 4; ++kq) A2v[kq] = *((const bf16x8*)(wp + 32 + kq * 16));
  float b2r[6];
#pragma unroll
  for (int i = 0; i < 6; ++i) b2r[i] = gb2[i];

  // xs (stage-0 input), then fold b2 into bases
  float xs[6], sgnLp[6], xs005[6];
#pragma unroll
  for (int f = 0; f < 6; ++f) {
    float sl = sgn * Lc[f];
    xs[f] = x0c[f] + sl;
    sgnLp[f] = fmaf(0.01f, b2r[f], sl);           // dl base: sgnL + (dt/6)*6*b2
  }
  union { bf16x8 v; unsigned w[4]; } bx;
  bx.w[0] = u ? 0x00003F80u : pk2t(xs[0], xs[1]);
  bx.w[1] = pk2t(xs[2], xs[3]);
  bx.w[2] = pk2t(xs[4], xs[5]);
  bx.w[3] = uu_pk;
#pragma unroll
  for (int f = 0; f < 6; ++f) xs005[f] = fmaf(0.005f, b2r[f], xs[f]);

  f32x16 z16;
#pragma unroll
  for (int i = 0; i < 16; ++i) z16[i] = 0.0f;

  float ksum[4] = {0.f, 0.f, 0.f, 0.f};          // C-layout: regs 0-3 = feats 4u+0..3
#pragma unroll
  for (int st = 0; st < 4; ++st) {
    f32x16 d1a = __builtin_amdgcn_mfma_f32_32x32x16_bf16(A1v0, bx.v, z16, 0, 0, 0);
    f32x16 d1b = __builtin_amdgcn_mfma_f32_32x32x16_bf16(A1v1, bx.v, z16, 0, 0, 0);
    unsigned Hpk[16];
#pragma unroll
    for (int pr = 0; pr < 8; ++pr) Hpk[pr]     = tanh2_pk(d1a[2*pr], d1a[2*pr+1]);
#pragma unroll
    for (int pr = 0; pr < 8; ++pr) Hpk[8 + pr] = tanh2_pk(d1b[2*pr], d1b[2*pr+1]);
    // layer2: B-fragment = own Hpk[4kq..4kq+3] (hidden permutation at pack time)
    f32x16 d2 = z16;
#pragma unroll
    for (int kq = 0; kq < 4; ++kq) {
      union { bf16x8 v; unsigned w[4]; } bh;
      bh.w[0] = Hpk[4*kq+0]; bh.w[1] = Hpk[4*kq+1];
      bh.w[2] = Hpk[4*kq+2]; bh.w[3] = Hpk[4*kq+3];
      d2 = __builtin_amdgcn_mfma_f32_32x32x16_bf16(A2v[kq], bh.v, d2, 0, 0, 0);
    }
    const float wks = (st == 0 || st == 3) ? 1.0f : 2.0f;
#pragma unroll
    for (int g = 0; g < 4; ++g) ksum[g] = fmaf(wks, d2[g], ksum[g]);
    if (st < 3) {
      // xi for next stage: need all 6 feats per lane
      float e0 = __shfl_xor(d2[0], 32, 64);
      float e1 = __shfl_xor(d2[1], 32, 64);
      float e2 = __shfl_xor(d2[2], 32, 64);
      float e3 = __shfl_xor(d2[3], 32, 64);
      float k0 = u ? e0 : d2[0];
      float k1 = u ? e1 : d2[1];
      float k2 = u ? e2 : d2[2];
      float k3 = u ? e3 : d2[3];
      float k4 = u ? d2[0] : e0;
      float k5 = u ? d2[1] : e1;
      const float cin = (st == 2) ? 0.01f : 0.005f;
      float base0, base1, base2, base3, base4, base5;
      if (st == 2) {
        base0 = fmaf(0.005f, b2r[0], xs005[0]); base1 = fmaf(0.005f, b2r[1], xs005[1]);
        base2 = fmaf(0.005f, b2r[2], xs005[2]); base3 = fmaf(0.005f, b2r[3], xs005[3]);
        base4 = fmaf(0.005f, b2r[4], xs005[4]); base5 = fmaf(0.005f, b2r[5], xs005[5]);
      } else {
        base0 = xs005[0]; base1 = xs005[1]; base2 = xs005[2];
        base3 = xs005[3]; base4 = xs005[4]; base5 = xs005[5];
      }
      float xi0 = fmaf(cin, k0, base0), xi1 = fmaf(cin, k1, base1);
      float xi2 = fmaf(cin, k2, base2), xi3 = fmaf(cin, k3, base3);
      float xi4 = fmaf(cin, k4, base4), xi5 = fmaf(cin, k5, base5);
      bx.w[0] = u ? 0x00003F80u : pk2t(xi0, xi1);
      bx.w[1] = pk2t(xi2, xi3);
      bx.w[2] = pk2t(xi4, xi5);
    }
  }

  // deltas -> LDS in C-layout: u=0 writes feats 0-3, u=1 writes feats 4-5
  const float dt6 = 0.01f / 6.0f;
  if (u == 0) {
#pragma unroll
    for (int g = 0; g < 4; ++g) dxs[c * 17 + g] = fmaf(dt6, ksum[g], sgnLp[g]);
  } else {
#pragma unroll
    for (int g = 0; g < 2; ++g) dxs[c * 17 + 4 + g] = fmaf(dt6, ksum[g], sgnLp[4 + g]);
  }

  // ---- moments: two 16x16x32 MFMAs, shared B = dx ----
  float dxv[8];
#pragma unroll
  for (int j = 0; j < 8; ++j) dxv[j] = dxs[(8 * q16 + j) * 17 + m16];
  float wc0[8], wc1[8];
#pragma unroll
  for (int j = 0; j < 8; ++j) {
    float c0j = (j == 0) ? -0.25f : ONE3;
    float c1j = (j <= 4) ? ONE3 : 0.0f;
    wc0[j] = (q16 == 0) ? c0j : ((q16 == 1) ? c1j : 0.0f);
    wc1[j] = (q16 == 2) ? c0j : ((q16 == 3) ? c1j : 0.0f);
  }
  float wm00 = (q16 == 0) ? -3.0f : wc0[0];
  float wm10 = (q16 == 2) ? -3.0f : wc1[0];
  bool mlt6 = (m16 < 6), m6 = (m16 == 6), m7 = (m16 == 7);
  union { bf16x8 v; unsigned w[4]; } am0, am1, bw;
  {
    float a0[8], a1[8];
#pragma unroll
    for (int j = 0; j < 8; ++j) {
      float wmj0 = (j == 0) ? wm00 : wc0[j];
      float wmj1 = (j == 0) ? wm10 : wc1[j];
      float alt0 = m6 ? wc0[j] : (m7 ? wmj0 : 0.0f);
      float alt1 = m6 ? wc1[j] : (m7 ? wmj1 : 0.0f);
      a0[j] = mlt6 ? wc0[j] * dxv[j] : alt0;
      a1[j] = mlt6 ? wc1[j] * dxv[j] : alt1;
    }
#pragma unroll
    for (int pr = 0; pr < 4; ++pr) {
      am0.w[pr] = pk2(a0[2*pr], a0[2*pr+1]);
      am1.w[pr] = pk2(a1[2*pr], a1[2*pr+1]);
      bw.w[pr]  = pk2(dxv[2*pr], dxv[2*pr+1]);
    }
  }
  f32x4 zz = {0.0f, 0.0f, 0.0f, 0.0f};
  f32x4 Dm0 = __builtin_amdgcn_mfma_f32_16x16x32_bf16(am0.v, bw.v, zz, 0, 0, 0);
  f32x4 Dm1 = __builtin_amdgcn_mfma_f32_16x16x32_bf16(am1.v, bw.v, zz, 0, 0, 0);

  if (q16 < 2 && m16 < 6) {
    float* u0 = Ubuf + (size_t)(2 * p) * 48;
    float* u1 = Ubuf + (size_t)(2 * p + 1) * 48;
#pragma unroll
    for (int i = 0; i < 4; ++i) {
      u0[(4 * q16 + i) * 6 + m16] = Dm0[i];
      u1[(4 * q16 + i) * 6 + m16] = Dm1[i];
    }
  }
}

// ---- epilogue: 1 thread/batch ----
__global__ void ukf_epi(const float* __restrict__ gx,
                        const float* __restrict__ gy,
                        const char*  __restrict__ ws,
                        const float* __restrict__ Ubuf,
                        float* __restrict__ out, int B) {
  int b = blockIdx.x * blockDim.x + threadIdx.x;
  if (b >= B) return;
  const float* rec = Ubuf + (size_t)b * 48;
  float U[21], cbv[6], dbv[6];
#pragma unroll
  for (int i = 0; i < 6; ++i)
#pragma unroll
    for (int j = 0; j <= i; ++j) U[TRI(i,j)] = rec[i * 6 + j];
#pragma unroll
  for (int j = 0; j < 6; ++j) { cbv[j] = rec[36 + j]; dbv[j] = rec[42 + j]; }

  float x0[6];
  {
    const float* xb = gx + (size_t)b * 6;
    float2 t0 = *(const float2*)(xb);
    float2 t1 = *(const float2*)(xb + 2);
    float2 t2 = *(const float2*)(xb + 4);
    x0[0]=t0.x; x0[1]=t0.y; x0[2]=t1.x; x0[3]=t1.y; x0[4]=t2.x; x0[5]=t2.y;
  }
  const float* yb = gy + (size_t)b * 3;
  float yy0 = yb[0], yy1 = yb[1], yy2 = yb[2];

  const float* qro = (const float*)(ws + QOFF);
  float Qm[21], Rm[6];
#pragma unroll
  for (int t = 0; t < 21; ++t) Qm[t] = qro[t];
#pragma unroll
  for (int t = 0; t < 6; ++t) Rm[t] = qro[21 + t];

  float xp[6];
#pragma unroll
  for (int i = 0; i < 6; ++i) xp[i] = x0[i] + dbv[i];
  float D[21];
#pragma unroll
  for (int i = 0; i < 6; ++i)
#pragma unroll
    for (int j = 0; j <= i; ++j) {
      float v = U[TRI(i,j)];
      v -= cbv[i] * dbv[j];
      v -= dbv[i] * cbv[j];
      v = fmaf(3.75f * dbv[i], dbv[j], v);
      D[TRI(i,j)] = v;
    }
  float s00 = D[TRI(0,0)] + Rm[TRI(0,0)];
  float s10 = D[TRI(1,0)] + Rm[TRI(1,0)];
  float s11 = D[TRI(1,1)] + Rm[TRI(1,1)];
  float s20 = D[TRI(2,0)] + Rm[TRI(2,0)];
  float s21 = D[TRI(2,1)] + Rm[TRI(2,1)];
  float s22 = D[TRI(2,2)] + Rm[TRI(2,2)];
  float a00 = s00 + 1e-5f, a11 = s11 + 1e-5f, a22 = s22 + 1e-5f;
  float a10 = s10, a20 = s20, a21 = s21;
  float adj00 = a11*a22 - a21*a21;
  float adj01 = a20*a21 - a10*a22;
  float adj02 = a10*a21 - a11*a20;
  float adj11 = a00*a22 - a20*a20;
  float adj12 = a10*a20 - a00*a21;
  float adj22 = a00*a11 - a10*a10;
  float det  = a00*adj00 + a10*adj01 + a20*adj02;
  float idet = 1.0f / det;
  float I00 = adj00*idet, I01 = adj01*idet, I02 = adj02*idet;
  float I11 = adj11*idet, I12 = adj12*idet, I22 = adj22*idet;

#define DS(i,j) ((i) >= (j) ? D[TRI(i,j)] : D[TRI(j,i)])
  float K_[18];
#pragma unroll
  for (int i = 0; i < 6; ++i) {
    float c0 = DS(i,0), c1 = DS(i,1), c2 = DS(i,2);
    K_[i*3+0] = c0*I00 + c1*I01 + c2*I02;
    K_[i*3+1] = c0*I01 + c1*I11 + c2*I12;
    K_[i*3+2] = c0*I02 + c1*I12 + c2*I22;
  }
  float inn0 = yy0 - xp[0], inn1 = yy1 - xp[1], inn2 = yy2 - xp[2];
  float xu[6];
#pragma unroll
  for (int i = 0; i < 6; ++i)
    xu[i] = xp[i] + K_[i*3]*inn0 + K_[i*3+1]*inn1 + K_[i*3+2]*inn2;

  float KS[18];
#pragma unroll
  for (int i = 0; i < 6; ++i) {
    float k0 = K_[i*3], k1 = K_[i*3+1], k2 = K_[i*3+2];
    KS[i*3+0] = k0*s00 + k1*s10 + k2*s20;
    KS[i*3+1] = k0*s10 + k1*s11 + k2*s21;
    KS[i*3+2] = k0*s20 + k1*s21 + k2*s22;
  }
  float Pu[21];
#pragma unroll
  for (int i = 0; i < 6; ++i)
#pragma unroll
    for (int j = 0; j <= i; ++j) {
      float v = D[TRI(i,j)] + Qm[TRI(i,j)];
      v -= KS[i*3]*K_[j*3] + KS[i*3+1]*K_[j*3+1] + KS[i*3+2]*K_[j*3+2];
      Pu[TRI(i,j)] = v + ((i==j) ? 1e-4f : 0.0f);
    }

  float* o_xu = out;
  float* o_Pu = out + (size_t)6  * B;
  float* o_xp = out + (size_t)42 * B;
  float* o_Pp = out + (size_t)48 * B;
  float* o_yp = out + (size_t)84 * B;
  float* o_S  = out + (size_t)87 * B;
  float* o_K  = out + (size_t)96 * B;
  {
    float* pp = o_xu + (size_t)b * 6;
    ((float2*)pp)[0] = make_float2(xu[0], xu[1]);
    ((float2*)pp)[1] = make_float2(xu[2], xu[3]);
    ((float2*)pp)[2] = make_float2(xu[4], xu[5]);
  }
  {
    float* pp = o_Pu + (size_t)b * 36;
#pragma unroll
    for (int i = 0; i < 6; ++i)
#pragma unroll
      for (int j = 0; j < 6; j += 2) {
        float v0 = (i>=j)   ? Pu[TRI(i,j)]   : Pu[TRI(j,i)];
        float v1 = (i>=j+1) ? Pu[TRI(i,j+1)] : Pu[TRI(j+1,i)];
        *(float2*)(pp + i*6 + j) = make_float2(v0, v1);
      }
  }
  {
    float* pp = o_xp + (size_t)b * 6;
    ((float2*)pp)[0] = make_float2(xp[0], xp[1]);
    ((float2*)pp)[1] = make_float2(xp[2], xp[3]);
    ((float2*)pp)[2] = make_float2(xp[4], xp[5]);
  }
  {
    float* pp = o_Pp + (size_t)b * 36;
#pragma unroll
    for (int i = 0; i < 6; ++i)
#pragma unroll
      for (int j = 0; j < 6; j += 2) {
        float v0 = ((i>=j)   ? D[TRI(i,j)]   : D[TRI(j,i)])   + ((i>=j)   ? Qm[TRI(i,j)]   : Qm[TRI(j,i)]);
        float v1 = ((i>=j+1) ? D[TRI(i,j+1)] : D[TRI(j+1,i)]) + ((i>=j+1) ? Qm[TRI(i,j+1)] : Qm[TRI(j+1,i)]);
        *(float2*)(pp + i*6 + j) = make_float2(v0, v1);
      }
  }
  {
    float* pp = o_yp + (size_t)b * 3;
    pp[0] = xp[0]; pp[1] = xp[1]; pp[2] = xp[2];
  }
  {
    float* pp = o_S + (size_t)b * 9;
    pp[0]=s00; pp[1]=s10; pp[2]=s20;
    pp[3]=s10; pp[4]=s11; pp[5]=s21;
    pp[6]=s20; pp[7]=s21; pp[8]=s22;
  }
  {
    float* pp = o_K + (size_t)b * 18;
#pragma unroll
    for (int i = 0; i < 9; ++i)
      ((float2*)pp)[i] = make_float2(K_[i*2], K_[i*2+1]);
  }
}

extern "C" void kernel_launch(void* const* d_in, const int* in_sizes, int n_in,
                              void* d_out, int out_size, void* d_ws, size_t ws_size,
                              hipStream_t stream) {
  const float* x  = (const float*)d_in[0];
  const float* P  = (const float*)d_in[1];
  const float* u  = (const float*)d_in[2];
  const float* y  = (const float*)d_in[3];
  const float* LQ = (const float*)d_in[4];
  const float* LR = (const float*)d_in[5];
  const float* W1 = (const float*)d_in[6];
  const float* b1 = (const float*)d_in[7];
  const float* W2 = (const float*)d_in[8];
  const float* b2 = (const float*)d_in[9];
  float* out = (float*)d_out;
  char*  ws  = (char*)d_ws;
  int B = in_sizes[0] / 6;

  float* Lbuf = (float*)(ws + LOFF);
  float* Ubuf = (float*)(ws + LOFF + (size_t)B * 160);

  hipLaunchKernelGGL(prep_kernel, dim3((B + 255) / 256), dim3(256), 0, stream,
                     P, W1, b1, W2, LQ, LR, ws, Lbuf, B);
  hipLaunchKernelGGL(ukf_main, dim3((B + 7) / 8), dim3(256), 0, stream,
                     x, u, b2, (const float*)Lbuf, (const char*)ws, Ubuf, B);
  hipLaunchKernelGGL(ukf_epi, dim3((B + 255) / 256), dim3(256), 0, stream,
                     x, y, (const char*)ws, (const float*)Ubuf, out, B);
}